// Round 12
// baseline (612.227 us; speedup 1.0000x reference)
//
#include <hip/hip_runtime.h>
#include <math.h>

#define NB 16
#define SL 32
#define H5 5120
#define K3 3072

typedef __attribute__((ext_vector_type(8))) short short8;
typedef __attribute__((ext_vector_type(4))) float floatx4;
typedef __attribute__((ext_vector_type(4))) int intx4;

__device__ __forceinline__ float sigf(float x) { return 1.0f / (1.0f + expf(-x)); }

__device__ __forceinline__ unsigned short f2bf(float x) {
  union { float f; unsigned int u; } v;
  v.f = x;
  unsigned int r = v.u + 0x7FFFu + ((v.u >> 16) & 1u);
  return (unsigned short)(r >> 16);
}

// ---- direct-poll all-to-all barrier (minimum L3 hops) ----------------------
// Round-11 lesson: barrier cost = serialized L3 round-trips. Monitor scheme
// had 3 (arrival -> monitor poll -> gen -> spin); counter had 2. This has 1:
// every block stores its own flag (distinct addrs, no RMW) and ITSELF polls
// all flags with dwordx4 sc-loads. Detection = one L3 RT after last arrival.
// Cross-block DATA uses sc0sc1 ops; vmcnt(0) drains them before arrival.

// 32-flag variant (per-dir scan).
__device__ __forceinline__ void bar32(int* flags, int idx, int mygen) {
  asm volatile("s_waitcnt vmcnt(0)" ::: "memory");
  __syncthreads();
  const int tid = threadIdx.x;
  if (tid == 0)
    __hip_atomic_store(&flags[idx], mygen, __ATOMIC_RELAXED,
                       __HIP_MEMORY_SCOPE_AGENT);
  if (tid < 64) {
    const int off = (tid & 7) * 4;     // lanes 8-63 duplicate slices 0-7
    int ok;
    do {
      intx4 f;
      asm volatile("global_load_dwordx4 %0, %1, off sc0 sc1\n\t"
                   "s_waitcnt vmcnt(0)"
                   : "=&v"(f) : "v"(flags + off) : "memory");
      ok = (f.x >= mygen) & (f.y >= mygen) & (f.z >= mygen) & (f.w >= mygen);
    } while (__all(ok) == 0);
  }
  __syncthreads();
}

// 512-flag variant (rounds).
__device__ __forceinline__ void bar512(int* flags, int idx, int mygen) {
  asm volatile("s_waitcnt vmcnt(0)" ::: "memory");
  __syncthreads();
  const int tid = threadIdx.x;
  if (tid == 0)
    __hip_atomic_store(&flags[idx], mygen, __ATOMIC_RELAXED,
                       __HIP_MEMORY_SCOPE_AGENT);
  if (tid < 64) {
    int ok;
    do {
      intx4 f0, f1;
      asm volatile("global_load_dwordx4 %0, %2, off sc0 sc1\n\t"
                   "global_load_dwordx4 %1, %3, off sc0 sc1\n\t"
                   "s_waitcnt vmcnt(0)"
                   : "=&v"(f0), "=&v"(f1)
                   : "v"(flags + tid * 8), "v"(flags + tid * 8 + 4)
                   : "memory");
      ok = (f0.x >= mygen) & (f0.y >= mygen) & (f0.z >= mygen) & (f0.w >= mygen)
         & (f1.x >= mygen) & (f1.y >= mygen) & (f1.z >= mygen) & (f1.w >= mygen);
    } while (__all(ok) == 0);
  }
  __syncthreads();
}

// meta layout (ints):
//  own 0, lt 512, li 1024, rt 1536, ri 2048, dep 2560, nn 3072(16),
//  dcnt 3088(32), lcnt 3120(32), dlist 3152(32*512), llist 19536(32*512)

// ---------------- zero ----------------
__global__ void k_zero(float* __restrict__ p, int n) {
  int i = blockIdx.x * blockDim.x + threadIdx.x;
  if (i < n) p[i] = 0.0f;
}

// ---------------- batch f32 -> bf16 conversion (6 segments) ----------------
__global__ void k_conv6(const float* s0, unsigned short* d0, int n0,
                        const float* s1, unsigned short* d1, int n1,
                        const float* s2, unsigned short* d2, int n2,
                        const float* s3, unsigned short* d3, int n3,
                        const float* s4, unsigned short* d4, int n4,
                        const float* s5, unsigned short* d5, int n5)
{
  const float* s; unsigned short* d; int n;
  switch (blockIdx.y) {
    case 0: s = s0; d = d0; n = n0; break;
    case 1: s = s1; d = d1; n = n1; break;
    case 2: s = s2; d = d2; n = n2; break;
    case 3: s = s3; d = d3; n = n3; break;
    case 4: s = s4; d = d4; n = n4; break;
    default: s = s5; d = d5; n = n5; break;
  }
  const int nf4 = n >> 2;
  for (int i = blockIdx.x * blockDim.x + threadIdx.x; i < nf4; i += gridDim.x * blockDim.x) {
    const float4 v = *(const float4*)&s[i * 4];
    ushort4 o;
    o.x = f2bf(v.x); o.y = f2bf(v.y); o.z = f2bf(v.z); o.w = f2bf(v.w);
    *(ushort4*)&d[i * 4] = o;
  }
}

// ---- generic f32 GEMM (only used for E1): out[r,g] = sum_k A[r,k]*W[g,k]
__global__ __launch_bounds__(256)
void k_gemm(const float* __restrict__ A, int lda,
            const float* __restrict__ W, int ldw,
            float* __restrict__ out, int N, int K)
{
  __shared__ __align__(16) float sm[2 * 16 * 68];
  float* As = sm;
  float* Ws = sm + 16 * 68;
  const int tid = threadIdx.x;
  const int tx = tid & 15, ty = tid >> 4;
  const int g0 = blockIdx.x * 64, r0 = blockIdx.y * 64;
  float acc[4][4];
#pragma unroll
  for (int i = 0; i < 4; ++i)
#pragma unroll
    for (int j = 0; j < 4; ++j) acc[i][j] = 0.0f;
  const int ks = tid & 15, rr = tid >> 4;
  for (int kt = 0; kt < K; kt += 16) {
#pragma unroll
    for (int rep = 0; rep < 4; ++rep) {
      As[ks * 68 + rep * 16 + rr] = A[(size_t)(r0 + rep * 16 + rr) * lda + kt + ks];
      Ws[ks * 68 + rep * 16 + rr] = W[(size_t)(g0 + rep * 16 + rr) * ldw + kt + ks];
    }
    __syncthreads();
#pragma unroll
    for (int k = 0; k < 16; ++k) {
      const float4 a4 = *(const float4*)&As[k * 68 + ty * 4];
      const float4 w4 = *(const float4*)&Ws[k * 68 + tx * 4];
      const float av[4] = {a4.x, a4.y, a4.z, a4.w};
      const float wv[4] = {w4.x, w4.y, w4.z, w4.w};
#pragma unroll
      for (int i = 0; i < 4; ++i)
#pragma unroll
        for (int j = 0; j < 4; ++j) acc[i][j] += av[i] * wv[j];
    }
    __syncthreads();
  }
#pragma unroll
  for (int i = 0; i < 4; ++i) {
    const int r = r0 + ty * 4 + i;
    float4 o;
    o.x = acc[i][0]; o.y = acc[i][1]; o.z = acc[i][2]; o.w = acc[i][3];
    *(float4*)&out[(size_t)r * N + g0 + tx * 4] = o;
  }
}

// ---------------- input projection MFMA: X = embB @ WihB^T ----------------
__global__ __launch_bounds__(256)
void k_xproj(const unsigned short* __restrict__ embB,
             const unsigned short* __restrict__ WfB, const unsigned short* __restrict__ WbB,
             float* __restrict__ Xf, float* __restrict__ Xb)
{
  const unsigned short* B = blockIdx.z ? WbB : WfB;
  float* out = blockIdx.z ? Xb : Xf;
  __shared__ __align__(16) unsigned short As[128 * 40];
  __shared__ __align__(16) unsigned short Bs[128 * 40];
  const int tid = threadIdx.x;
  const int g0 = blockIdx.x * 128;
  const int r0 = blockIdx.y * 128;
  const int wave = tid >> 6, lane = tid & 63;
  const int wm = wave >> 1, wn = wave & 1;
  const int l15 = lane & 15, quad = lane >> 4;
  floatx4 acc[4][4];
#pragma unroll
  for (int mt = 0; mt < 4; ++mt)
#pragma unroll
    for (int nt = 0; nt < 4; ++nt) acc[mt][nt] = (floatx4){0.f, 0.f, 0.f, 0.f};
  for (int kt = 0; kt < 512; kt += 32) {
    __syncthreads();
#pragma unroll
    for (int p = 0; p < 2; ++p) {
      const int i = tid + p * 256;
      const int row = i >> 2, q = i & 3;
      *(uint4*)&As[row * 40 + q * 8] = *(const uint4*)&embB[(size_t)(r0 + row) * 512 + kt + q * 8];
      *(uint4*)&Bs[row * 40 + q * 8] = *(const uint4*)&B[(size_t)(g0 + row) * 512 + kt + q * 8];
    }
    __syncthreads();
    short8 af[4], bfr[4];
#pragma unroll
    for (int mt = 0; mt < 4; ++mt)
      af[mt] = *(const short8*)&As[(wm * 64 + mt * 16 + l15) * 40 + quad * 8];
#pragma unroll
    for (int nt = 0; nt < 4; ++nt)
      bfr[nt] = *(const short8*)&Bs[(wn * 64 + nt * 16 + l15) * 40 + quad * 8];
#pragma unroll
    for (int mt = 0; mt < 4; ++mt)
#pragma unroll
      for (int nt = 0; nt < 4; ++nt)
        acc[mt][nt] = __builtin_amdgcn_mfma_f32_16x16x32_bf16(af[mt], bfr[nt], acc[mt][nt], 0, 0, 0);
  }
#pragma unroll
  for (int nt = 0; nt < 4; ++nt) {
    const int col = g0 + wn * 64 + nt * 16 + l15;
#pragma unroll
    for (int mt = 0; mt < 4; ++mt)
#pragma unroll
      for (int i = 0; i < 4; ++i) {
        const int row = r0 + wm * 64 + mt * 16 + quad * 4 + i;
        out[(size_t)row * 2048 + col] = acc[mt][nt][i];
      }
  }
}

// ---------------- big compose GEMM: gB[r,g] = bc[g] + U @ WcB^T ----------------
__global__ __launch_bounds__(256)
void k_mfma_gemm(const unsigned short* __restrict__ U, const unsigned short* __restrict__ WcB,
                 const float* __restrict__ bc, float* __restrict__ gB)
{
  __shared__ __align__(16) unsigned short As[128 * 40];
  __shared__ __align__(16) unsigned short Bs[64 * 40];
  const int bid = blockIdx.x;
  const int r0 = (bid / 80) * 128;
  const int g0 = (bid % 80) * 64;
  const int tid = threadIdx.x;
  const int wave = tid >> 6, lane = tid & 63;
  const int wm = wave >> 1, wn = wave & 1;
  const int l15 = lane & 15, quad = lane >> 4;
  floatx4 acc[4][2];
#pragma unroll
  for (int mf = 0; mf < 4; ++mf)
#pragma unroll
    for (int nt = 0; nt < 2; ++nt) acc[mf][nt] = (floatx4){0.f, 0.f, 0.f, 0.f};
  const int a_row = tid >> 2, a_q = tid & 3;
  for (int kt = 0; kt < K3; kt += 32) {
    __syncthreads();
#pragma unroll
    for (int p = 0; p < 2; ++p) {
      const int i = tid + p * 256;
      const int row = i >> 2, q = i & 3;
      *(uint4*)&As[row * 40 + q * 8] = *(const uint4*)&U[(size_t)(r0 + row) * K3 + kt + q * 8];
    }
    *(uint4*)&Bs[a_row * 40 + a_q * 8] = *(const uint4*)&WcB[(size_t)(g0 + a_row) * K3 + kt + a_q * 8];
    __syncthreads();
    short8 af[4], bfr[2];
#pragma unroll
    for (int mf = 0; mf < 4; ++mf)
      af[mf] = *(const short8*)&As[(wm * 64 + mf * 16 + l15) * 40 + quad * 8];
#pragma unroll
    for (int nt = 0; nt < 2; ++nt)
      bfr[nt] = *(const short8*)&Bs[(wn * 32 + nt * 16 + l15) * 40 + quad * 8];
#pragma unroll
    for (int mf = 0; mf < 4; ++mf)
#pragma unroll
      for (int nt = 0; nt < 2; ++nt)
        acc[mf][nt] = __builtin_amdgcn_mfma_f32_16x16x32_bf16(af[mf], bfr[nt], acc[mf][nt], 0, 0, 0);
  }
#pragma unroll
  for (int nt = 0; nt < 2; ++nt) {
    const int col = g0 + wn * 32 + nt * 16 + l15;
    const float bias = bc[col];
#pragma unroll
    for (int mf = 0; mf < 4; ++mf)
#pragma unroll
      for (int i = 0; i < 4; ++i) {
        const int row = r0 + wm * 64 + mf * 16 + quad * 4 + i;
        gB[(size_t)row * H5 + col] = acc[mf][nt][i] + bias;
      }
  }
}

// ---------------- fused 32-step bidirectional LSTM scan (plain launch) ------
// grid 64: block = (dir, hjt). Per-DIR direct-poll barriers (32 flags).
// Cross-block data = hbB only (sc0sc1). X-row loads issued BEFORE the h-load
// wait so their L2 latency folds into the L3 h-load wait.
__global__ __launch_bounds__(256)
void k_scan(const float* __restrict__ Xf, const float* __restrict__ Xb,
            const unsigned short* __restrict__ WhfB, const unsigned short* __restrict__ WhbB,
            const float* __restrict__ bf, const float* __restrict__ bb,
            const int* __restrict__ len,
            unsigned short* __restrict__ hbB, float* __restrict__ cbuf,
            float* __restrict__ hs, float* __restrict__ cs, int* __restrict__ bar)
{
  const int bid = blockIdx.x;
  const int dir = bid >> 5;
  const int hjt = bid & 31;
  const int tid = threadIdx.x;
  const int wave = tid >> 6, lane = tid & 63;
  const int l15 = lane & 15, quad = lane >> 4;
  const unsigned short* Wh = dir ? WhbB : WhfB;
  const float* bias = dir ? bb : bf;
  const float* X = dir ? Xb : Xf;
  int* myflags = &bar[512 + dir * 32];
  __shared__ float sg[4 * 16 * 17];
  const int jg = wave * 512 + hjt * 16 + l15;
  // time-invariant weight fragments: 16 x short8 = 64 VGPRs
  short8 wfr[16];
#pragma unroll
  for (int k8 = 0; k8 < 16; ++k8)
    wfr[k8] = *(const short8*)&Wh[(size_t)jg * 512 + k8 * 32 + quad * 8];
  // per-thread gate constants
  const int bb_ = tid >> 4, j = tid & 15;
  const int hj = hjt * 16 + j;
  const int Lb = len[bb_];
  const float bi_i = bias[hj];
  const float bi_f = bias[512 + hj];
  const float bi_g = bias[1024 + hj];
  const float bi_o = bias[1536 + hj];
  for (int t = 0; t < SL; ++t) {
    const int pp = t & 1;
    const unsigned short* hp = hbB + (size_t)(dir * 2 + pp) * 8192;
    unsigned short* hn = hbB + (size_t)(dir * 2 + (pp ^ 1)) * 8192;
    const float* cp = cbuf + (size_t)(dir * 2 + pp) * 8192;
    float* cn = cbuf + (size_t)(dir * 2 + (pp ^ 1)) * 8192;
    // X-row loads issued first (independent of h; wait folded into vmcnt(0))
    int xidx = t;
    if (dir) xidx = (t < Lb) ? (Lb - 1 - t) : t;
    const float* xr = X + (size_t)(bb_ * SL + xidx) * 2048;
    const float x0 = xr[hj];
    const float x1 = xr[512 + hj];
    const float x2 = xr[1024 + hj];
    const float x3 = xr[1536 + hj];
    const float cprev = cp[bb_ * 512 + hj];
    // coherent A-fragment loads (batch-issue, single wait)
    short8 afr[16];
#pragma unroll
    for (int k8 = 0; k8 < 16; ++k8)
      asm volatile("global_load_dwordx4 %0, %1, off sc0 sc1"
                   : "=&v"(afr[k8])
                   : "v"(&hp[(size_t)l15 * 512 + k8 * 32 + quad * 8]));
    asm volatile("s_waitcnt vmcnt(0)" ::: "memory");
    __builtin_amdgcn_sched_barrier(0);
    floatx4 acc = (floatx4){0.f, 0.f, 0.f, 0.f};
#pragma unroll
    for (int k8 = 0; k8 < 16; ++k8)
      acc = __builtin_amdgcn_mfma_f32_16x16x32_bf16(afr[k8], wfr[k8], acc, 0, 0, 0);
#pragma unroll
    for (int i = 0; i < 4; ++i)
      sg[wave * 272 + (quad * 4 + i) * 17 + l15] = acc[i];
    __syncthreads();
    const float gi = sg[0 * 272 + bb_ * 17 + j] + x0 + bi_i;
    const float gf = sg[1 * 272 + bb_ * 17 + j] + x1 + bi_f;
    const float gg = sg[2 * 272 + bb_ * 17 + j] + x2 + bi_g;
    const float go = sg[3 * 272 + bb_ * 17 + j] + x3 + bi_o;
    const float cnew = sigf(gf) * cprev + sigf(gi) * tanhf(gg);
    const float hnew = sigf(go) * tanhf(cnew);
    cn[bb_ * 512 + hj] = cnew;
    const unsigned int hb16 = f2bf(hnew);
    asm volatile("global_store_short %0, %1, off sc0 sc1"
                 :: "v"(&hn[bb_ * 512 + hj]), "v"(hb16) : "memory");
    const int pos = dir ? xidx : t;
    const int col = dir ? (512 + hj) : hj;
    hs[(size_t)(bb_ * SL + pos) * 1024 + col] = hnew;
    cs[(size_t)(bb_ * SL + pos) * 1024 + col] = cnew;
    if (t != SL - 1) bar32(myflags, hjt, t + 1);
  }
}

// ---------------- precompute ALL segment argmax splits ----------------
__global__ __launch_bounds__(256)
void k_score(const float* __restrict__ E1, const float* __restrict__ Wr1,
             const float* __restrict__ Wr2, const int* __restrict__ len,
             int* __restrict__ ksplit)
{
  const int b = blockIdx.x;
  const int s = blockIdx.y;
  const int L = len[b];
  if (s + 2 > L) return;
  const int tid = threadIdx.x;
  __shared__ float e[32 * 257];
  __shared__ float w1p[256];
  __shared__ float w2s[256];
  __shared__ float red[32 * 8];
  __shared__ float sc[32];
  const int nrow = 32 - s;
  for (int i = tid; i < nrow * 256; i += 256) {
    const int rr = i >> 8, q = i & 255;
    e[rr * 257 + q] = E1[(size_t)(b * SL + s + rr) * 256 + q];
  }
  w1p[tid] = Wr1[tid * 513 + 512];
  w2s[tid] = Wr2[tid];
  __syncthreads();
  const int t_ = tid & 31, jg = tid >> 5;
  const int lmax = L - s;
  for (int l = 2; l <= lmax; ++l) {
    float part = 0.0f;
    if (t_ < l) {
      const float pos = 2.0f * (float)t_ / (float)l - 1.0f;
      const float* er = e + t_ * 257;
      for (int q = jg * 32; q < jg * 32 + 32; ++q) {
        const float v = er[q] + pos * w1p[q];
        part += fmaxf(v, 0.0f) * w2s[q];
      }
    }
    red[t_ * 8 + jg] = part;
    __syncthreads();
    if (jg == 0 && t_ < l) {
      float su = 0.0f;
      for (int q = 0; q < 8; ++q) su += red[t_ * 8 + q];
      sc[t_] = su;
    }
    __syncthreads();
    if (tid == 0) {
      int k = 0;
      float best = sc[0];
      for (int q = 1; q < l; ++q)
        if (sc[q] > best) { best = sc[q]; k = q; }
      ksplit[(b * 32 + s) * 33 + l] = k;
    }
    __syncthreads();
  }
}

// ---------------- DFS walk using precomputed splits ----------------
__global__ __launch_bounds__(64)
void k_walk(const int* __restrict__ ksplit, const int* __restrict__ len,
            int* __restrict__ meta)
{
  const int b = blockIdx.x;
  const int tid = threadIdx.x;
  __shared__ int ks[32 * 33];
  __shared__ int stk[96];
  for (int i = tid; i < 32 * 33; i += 64) ks[i] = ksplit[b * 1056 + i];
  __syncthreads();
  if (tid != 0) return;
  int* own = meta;
  int* lt = meta + 512;
  int* li = meta + 1024;
  int* rt = meta + 1536;
  int* ri = meta + 2048;
  int* dep = meta + 2560;
  int* nn = meta + 3072;
  int* dcnt = meta + 3088;
  int* lcnt = meta + 3120;
  int* dlist = meta + 3152;
  int* llist = meta + 19536;
  int sp = 0, nn_ = 1;
  stk[0] = 0; stk[1] = len[b]; stk[2] = 0;
  sp = 1;
  while (sp > 0) {
    sp--;
    const int s = stk[sp * 3], eN = stk[sp * 3 + 1], nid = stk[sp * 3 + 2];
    const int l = eN - s;
    const int k = ks[s * 33 + l];
    const int m = b * 32 + nid;
    own[m] = s + k;
    if (k == 0) { lt[m] = 0; li[m] = 0; }
    else if (k == 1) { lt[m] = 1; li[m] = s; }
    else {
      const int id = nn_++;
      lt[m] = 2; li[m] = id;
      stk[sp * 3] = s; stk[sp * 3 + 1] = s + k; stk[sp * 3 + 2] = id; sp++;
    }
    const int rl = l - k - 1;
    if (rl == 0) { rt[m] = 0; ri[m] = 0; }
    else if (rl == 1) { rt[m] = 1; ri[m] = s + k + 1; }
    else {
      const int id = nn_++;
      rt[m] = 2; ri[m] = id;
      stk[sp * 3] = s + k + 1; stk[sp * 3 + 1] = eN; stk[sp * 3 + 2] = id; sp++;
    }
  }
  nn[b] = nn_;
  for (int i = nn_ - 1; i >= 0; --i) {
    const int m = b * 32 + i;
    int d = 1;
    if (lt[m] == 2) d = max(d, dep[b * 32 + li[m]] + 1);
    if (rt[m] == 2) d = max(d, dep[b * 32 + ri[m]] + 1);
    dep[m] = d;
  }
  for (int i = 0; i < nn_; ++i) {
    const int m = b * 32 + i;
    const int r = dep[m];
    const int idx = atomicAdd(&dcnt[r], 1);
    dlist[r * 512 + idx] = m;
    if (lt[m] == 2 || rt[m] == 2) {
      const int lx = atomicAdd(&lcnt[r], 1);
      llist[r * 512 + lx] = m;
    }
  }
}

// ---------------- build U (bf16) = [hl_leaf|0 , hr_leaf|0 , hx] per node ----------------
__global__ __launch_bounds__(256)
void k_ubuild(const float* __restrict__ hs, const int* __restrict__ meta,
              unsigned short* __restrict__ U)
{
  const int id = blockIdx.x, b = blockIdx.y;
  const int tid = threadIdx.x;
  const int* own = meta;
  const int* lt = meta + 512;
  const int* li = meta + 1024;
  const int* rt = meta + 1536;
  const int* ri = meta + 2048;
  const int* nn = meta + 3072;
  const int m = b * 32 + id;
  unsigned short* u = U + (size_t)m * K3;
  if (id >= nn[b]) {
    for (int i = tid; i < K3; i += 256) u[i] = 0;
    return;
  }
  const float* hl = (lt[m] == 1) ? hs + (size_t)(b * 32 + li[m]) * 1024 : nullptr;
  const float* hr = (rt[m] == 1) ? hs + (size_t)(b * 32 + ri[m]) * 1024 : nullptr;
  const float* hx = hs + (size_t)(b * 32 + own[m]) * 1024;
  for (int i = tid; i < 1024; i += 256) {
    u[i] = hl ? f2bf(hl[i]) : 0;
    u[1024 + i] = hr ? f2bf(hr[i]) : 0;
    u[2048 + i] = f2bf(hx[i]);
  }
}

// ---------------- fused tree rounds: hidden-index-partitioned ---------------
// grid 512: block owns hidden cols j0=2*bid, j0+1 and all five gate rows.
// Wc fragments in 64 VGPRs (round-invariant). Cross-block data = nodehb only
// (sc0sc1). One direct-poll barrier per round. Leaf children read zeroed zpad.
__global__ __launch_bounds__(256, 2)
void k_rounds(const unsigned short* __restrict__ WcB, const int* __restrict__ meta,
              unsigned short* __restrict__ nodehb,
              const float* __restrict__ gB, const float* __restrict__ cs,
              float* __restrict__ nodec,
              float* __restrict__ out, int* __restrict__ bar,
              const unsigned short* __restrict__ zpad)
{
  const int* lt = meta + 512;
  const int* li = meta + 1024;
  const int* rt = meta + 1536;
  const int* ri = meta + 2048;
  const int* dcnt = meta + 3088;
  const int* dlist = meta + 3152;
  __shared__ float scratch[4][16][16];   // [wave][node][col] 4KB
  __shared__ float gates[16][16];        // [node][col] c=2*g+jj (c<10 used)
  const int tid = threadIdx.x;
  const int bid = blockIdx.x;
  const int wave = tid >> 6, lane = tid & 63;
  const int l15 = lane & 15, quad = lane >> 4;
  const int j0 = bid * 2;
  const int cc = (l15 < 10) ? l15 : l15 - 10;
  const size_t wrow = (size_t)((cc >> 1) * 1024 + j0 + (cc & 1)) * K3;
  const int kbase = wave * 256 + quad * 8;
  // round-invariant Wc fragments: 16 x short8 = 64 VGPRs
  short8 wreg[16];
#pragma unroll
  for (int i = 0; i < 8; ++i) {
    wreg[i]     = *(const short8*)&WcB[wrow + kbase + i * 32];
    wreg[8 + i] = *(const short8*)&WcB[wrow + 1024 + kbase + i * 32];
  }
  const int rnd = tid >> 4, rc = tid & 15;
  int bgen = 0;
  for (int r = 1; r <= 31; ++r) {
    const int cnt = dcnt[r];
    if (cnt == 0) break;                 // depths contiguous from 1 -> done
    if (r >= 2) { ++bgen; bar512(bar, bid, bgen); }
    for (int c0 = 0; c0 < cnt; c0 += 16) {
      // gB prefetch (oldest load -> retired first; later waitcnts cover it)
      float gBv = 0.0f;
      if (rc < 10 && c0 + rnd < cnt) {
        const int nodeP = dlist[r * 512 + c0 + rnd];
        gBv = gB[(size_t)nodeP * H5 + (rc >> 1) * 1024 + j0 + (rc & 1)];
      }
      // per-lane child row pointers (zpad for leaf/absent children)
      const int ma = c0 + l15;
      const unsigned short* pl = zpad;
      const unsigned short* pr = zpad;
      if (ma < cnt) {
        const int node = dlist[r * 512 + ma];
        const int base = node & ~31;
        if (lt[node] == 2) pl = nodehb + (size_t)(base + li[node]) * 1024;
        if (rt[node] == 2) pr = nodehb + (size_t)(base + ri[node]) * 1024;
      }
      // coherent A loads: issue all 16, split-wait
      short8 al[8], ar[8];
#pragma unroll
      for (int i = 0; i < 8; ++i)
        asm volatile("global_load_dwordx4 %0, %1, off sc0 sc1"
                     : "=&v"(al[i]) : "v"(pl + kbase + i * 32));
#pragma unroll
      for (int i = 0; i < 8; ++i)
        asm volatile("global_load_dwordx4 %0, %1, off sc0 sc1"
                     : "=&v"(ar[i]) : "v"(pr + kbase + i * 32));
      floatx4 acc = (floatx4){0.f, 0.f, 0.f, 0.f};
      asm volatile("s_waitcnt vmcnt(8)" ::: "memory");
      __builtin_amdgcn_sched_barrier(0);
#pragma unroll
      for (int ks = 0; ks < 8; ++ks)
        acc = __builtin_amdgcn_mfma_f32_16x16x32_bf16(al[ks], wreg[ks], acc, 0, 0, 0);
      asm volatile("s_waitcnt vmcnt(0)" ::: "memory");
      __builtin_amdgcn_sched_barrier(0);
#pragma unroll
      for (int ks = 0; ks < 8; ++ks)
        acc = __builtin_amdgcn_mfma_f32_16x16x32_bf16(ar[ks], wreg[8 + ks], acc, 0, 0, 0);
      __syncthreads();   // scratch safe to overwrite (prev chunk consumed)
#pragma unroll
      for (int i = 0; i < 4; ++i)
        scratch[wave][quad * 4 + i][l15] = acc[i];
      __syncthreads();
      if (rc < 10)
        gates[rnd][rc] = gBv + scratch[0][rnd][rc] + scratch[1][rnd][rc]
                             + scratch[2][rnd][rc] + scratch[3][rnd][rc];
      __syncthreads();
      if (tid < 16) {
        const int mc = c0 + tid;
        if (mc < cnt) {
          const int node = dlist[r * 512 + mc];
          const int base = node & ~31;
          const int ltv = lt[node], rtv = rt[node];
          const float* clp = (ltv == 2) ? &nodec[(size_t)(base + li[node]) * 1024]
                           : (ltv == 1) ? &cs[(size_t)(base + li[node]) * 1024] : nullptr;
          const float* crp = (rtv == 2) ? &nodec[(size_t)(base + ri[node]) * 1024]
                           : (rtv == 1) ? &cs[(size_t)(base + ri[node]) * 1024] : nullptr;
          unsigned int pk = 0;
#pragma unroll
          for (int jj = 0; jj < 2; ++jj) {
            const int j = j0 + jj;
            const float gi  = gates[tid][0 + jj];
            const float gfl = gates[tid][2 + jj];
            const float gfr = gates[tid][4 + jj];
            const float gu  = gates[tid][6 + jj];
            const float go  = gates[tid][8 + jj];
            const float cl = clp ? clp[j] : 0.0f;
            const float cr = crp ? crp[j] : 0.0f;
            const float c_ = sigf(gfl) * cl + sigf(gfr) * cr + sigf(gi) * tanhf(gu);
            const float h  = sigf(go) * tanhf(c_);
            nodec[(size_t)node * 1024 + j] = c_;   // block-local bytes: plain
            pk |= ((unsigned int)f2bf(h)) << (16 * jj);
            if ((node & 31) == 0) {
              const int b = node >> 5;
              out[b * 1024 + j] = h;
              out[16384 + b * 1024 + j] = c_;
            }
          }
          asm volatile("global_store_dword %0, %1, off sc0 sc1"
                       :: "v"(nodehb + (size_t)node * 1024 + j0), "v"(pk)
                       : "memory");
        }
      }
    }
  }
}

extern "C" void kernel_launch(void* const* d_in, const int* in_sizes, int n_in,
                              void* d_out, int out_size, void* d_ws, size_t ws_size,
                              hipStream_t stream) {
  const float* emb = (const float*)d_in[0];
  const int* len = (const int*)d_in[1];
  const float* Wihf = (const float*)d_in[2];
  const float* Whhf = (const float*)d_in[3];
  const float* bf = (const float*)d_in[4];
  const float* Wihb = (const float*)d_in[5];
  const float* Whhb = (const float*)d_in[6];
  const float* bb = (const float*)d_in[7];
  const float* Wr1 = (const float*)d_in[8];
  const float* Wr2 = (const float*)d_in[9];
  const float* Wc = (const float*)d_in[10];
  const float* bc = (const float*)d_in[11];
  float* out = (float*)d_out;

  float* ws = (float*)d_ws;
  float* Xf = ws;                                         // 1048576 f
  float* Xb = Xf + 1048576;                               // 1048576 f
  float* hs = Xb + 1048576;                               // 524288 f
  float* cs = hs + 524288;                                // 524288 f
  float* E1 = cs + 524288;                                // 131072 f
  unsigned short* U = (unsigned short*)(E1 + 131072);     // 786432 f
  float* gB = (float*)U + 786432;                         // 2621440 f
  float* nodeh = gB + 2621440;                            // 524288 f (unused)
  float* nodec = nodeh + 524288;                          // 524288 f
  unsigned short* nodehb = (unsigned short*)(nodec + 524288);     // 262144 f
  float* cbuf = (float*)nodehb + 262144;                  // 32768 f
  unsigned short* hbB = (unsigned short*)(cbuf + 32768);  // 16384 f
  unsigned short* WcB = (unsigned short*)((float*)hbB + 16384);   // 7864320 f
  unsigned short* WihfB = WcB + 15728640;                 // 1048576 sh
  unsigned short* WihbB = WihfB + 1048576;
  unsigned short* WhhfB = WihbB + 1048576;
  unsigned short* WhhbB = WhhfB + 1048576;
  unsigned short* embB = WhhbB + 1048576;                 // 262144 sh
  int* meta = (int*)(embB + 262144);                      // ~36K ints
  int* ksplit = meta + 36096;                             // 16*1056 ints
  int* bar = ksplit + 16896;                              // 1024 ints barrier state
  unsigned short* zpad = (unsigned short*)(bar + 1024);   // 1024 sh zeroed
  // bar layout: [0..511] rounds flags, [512..543] scan flags dir0,
  //             [544..575] scan flags dir1

  // zero c/h ping-pong state, per-depth counters, barrier state, zpad
  k_zero<<<192, 256, 0, stream>>>(cbuf, 49152);
  k_zero<<<1, 64, 0, stream>>>((float*)(meta + 3088), 64);
  k_zero<<<6, 256, 0, stream>>>((float*)bar, 1536);
  // bf16 conversions
  k_conv6<<<dim3(1920, 6), 256, 0, stream>>>(
      Wc, WcB, 15728640, Wihf, WihfB, 1048576, Wihb, WihbB, 1048576,
      Whhf, WhhfB, 1048576, Whhb, WhhbB, 1048576, emb, embB, 262144);
  // rank projection (f32)
  k_gemm<<<dim3(4, 8), 256, 0, stream>>>(emb, 512, Wr1, 513, E1, 256, 512);
  // input projections
  k_xproj<<<dim3(16, 4, 2), 256, 0, stream>>>(embB, WihfB, WihbB, Xf, Xb);
  // fused recurrent scan (plain launch: 64 blocks, per-dir direct-poll barriers)
  k_scan<<<64, 256, 0, stream>>>(Xf, Xb, WhhfB, WhhbB, bf, bb, len, hbB,
                                 cbuf, hs, cs, bar);
  // split table (parallel) + DFS walk (cheap)
  k_score<<<dim3(16, 31), 256, 0, stream>>>(E1, Wr1, Wr2, len, ksplit);
  k_walk<<<16, 64, 0, stream>>>(ksplit, len, meta);
  // precomputable part of every compose
  k_ubuild<<<dim3(32, 16), 256, 0, stream>>>(hs, meta, U);
  k_mfma_gemm<<<320, 256, 0, stream>>>(U, WcB, bc, gB);
  // fused tree rounds (plain launch: 512 blocks, 1 direct-poll barrier/round)
  k_rounds<<<512, 256, 0, stream>>>(WcB, meta, nodehb, gB, cs,
                                    nodec, out, bar, zpad);
}

// Round 13
// 550.059 us; speedup vs baseline: 1.1130x; 1.1130x over previous
//
#include <hip/hip_runtime.h>
#include <math.h>

#define NB 16
#define SL 32
#define H5 5120
#define K3 3072

typedef __attribute__((ext_vector_type(8))) short short8;
typedef __attribute__((ext_vector_type(4))) float floatx4;
typedef __attribute__((ext_vector_type(4))) int intx4;

__device__ __forceinline__ float sigf(float x) { return 1.0f / (1.0f + expf(-x)); }

__device__ __forceinline__ unsigned short f2bf(float x) {
  union { float f; unsigned int u; } v;
  v.f = x;
  unsigned int r = v.u + 0x7FFFu + ((v.u >> 16) & 1u);
  return (unsigned short)(r >> 16);
}

// ---- barrier variants (hybrid of best-measured per scale) ------------------
// 32-block: direct-poll all-to-all (r12: best for scan, 1 L3 hop).
__device__ __forceinline__ void bar32(int* flags, int idx, int mygen) {
  asm volatile("s_waitcnt vmcnt(0)" ::: "memory");
  __syncthreads();
  const int tid = threadIdx.x;
  if (tid == 0)
    __hip_atomic_store(&flags[idx], mygen, __ATOMIC_RELAXED,
                       __HIP_MEMORY_SCOPE_AGENT);
  if (tid < 64) {
    const int off = (tid & 7) * 4;
    int ok;
    do {
      intx4 f;
      asm volatile("global_load_dwordx4 %0, %1, off sc0 sc1\n\t"
                   "s_waitcnt vmcnt(0)"
                   : "=&v"(f) : "v"(flags + off) : "memory");
      ok = (f.x >= mygen) & (f.y >= mygen) & (f.z >= mygen) & (f.w >= mygen);
    } while (__all(ok) == 0);
  }
  __syncthreads();
}

// 512-block: monitor (r11: best for rounds — single poller avoids 512-way
// poll contention; r12's direct-poll regressed k_rounds <162 -> 170).
__device__ __forceinline__ void bar_rounds(int* flags, int* gen, int bid, int mygen) {
  asm volatile("s_waitcnt vmcnt(0)" ::: "memory");
  __syncthreads();
  const int tid = threadIdx.x;
  if (tid < 64) {
    if (tid == 0)
      __hip_atomic_store(&flags[bid], mygen, __ATOMIC_RELAXED,
                         __HIP_MEMORY_SCOPE_AGENT);
    if (bid == 0) {
      int ok;
      do {
        intx4 f0, f1;
        asm volatile("global_load_dwordx4 %0, %2, off sc0 sc1\n\t"
                     "global_load_dwordx4 %1, %3, off sc0 sc1\n\t"
                     "s_waitcnt vmcnt(0)"
                     : "=&v"(f0), "=&v"(f1)
                     : "v"(flags + tid * 8), "v"(flags + tid * 8 + 4)
                     : "memory");
        ok = (f0.x >= mygen) & (f0.y >= mygen) & (f0.z >= mygen) & (f0.w >= mygen)
           & (f1.x >= mygen) & (f1.y >= mygen) & (f1.z >= mygen) & (f1.w >= mygen);
      } while (__all(ok) == 0);
      if (tid == 0)
        __hip_atomic_store(gen, mygen, __ATOMIC_RELAXED,
                           __HIP_MEMORY_SCOPE_AGENT);
    } else if (tid == 0) {
      while (__hip_atomic_load(gen, __ATOMIC_RELAXED,
                               __HIP_MEMORY_SCOPE_AGENT) < mygen)
        __builtin_amdgcn_s_sleep(2);
    }
  }
  __syncthreads();
}

// meta layout (ints):
//  own 0, lt 512, li 1024, rt 1536, ri 2048, dep 2560, nn 3072(16),
//  dcnt 3088(32), lcnt 3120(32), dlist 3152(32*512), llist 19536(32*512)

// ---------------- merged zero (3 segments, one dispatch) ----------------
__global__ void k_zero3(float* a, int na, float* b, int nb_, float* c, int nc) {
  const int stride = gridDim.x * blockDim.x;
  int i = blockIdx.x * blockDim.x + threadIdx.x;
  for (int k = i; k < na; k += stride) a[k] = 0.0f;
  for (int k = i; k < nb_; k += stride) b[k] = 0.0f;
  for (int k = i; k < nc; k += stride) c[k] = 0.0f;
}

// ---------------- batch f32 -> bf16 conversion (6 segments) ----------------
__global__ void k_conv6(const float* s0, unsigned short* d0, int n0,
                        const float* s1, unsigned short* d1, int n1,
                        const float* s2, unsigned short* d2, int n2,
                        const float* s3, unsigned short* d3, int n3,
                        const float* s4, unsigned short* d4, int n4,
                        const float* s5, unsigned short* d5, int n5)
{
  const float* s; unsigned short* d; int n;
  switch (blockIdx.y) {
    case 0: s = s0; d = d0; n = n0; break;
    case 1: s = s1; d = d1; n = n1; break;
    case 2: s = s2; d = d2; n = n2; break;
    case 3: s = s3; d = d3; n = n3; break;
    case 4: s = s4; d = d4; n = n4; break;
    default: s = s5; d = d5; n = n5; break;
  }
  const int nf4 = n >> 2;
  for (int i = blockIdx.x * blockDim.x + threadIdx.x; i < nf4; i += gridDim.x * blockDim.x) {
    const float4 v = *(const float4*)&s[i * 4];
    ushort4 o;
    o.x = f2bf(v.x); o.y = f2bf(v.y); o.z = f2bf(v.z); o.w = f2bf(v.w);
    *(ushort4*)&d[i * 4] = o;
  }
}

// ---- E1 gemm body (f32): out[r,g] = sum_k A[r,k]*W[g,k]; lda=512 ldw=513
__device__ void gemm_body(const float* __restrict__ A, const float* __restrict__ W,
                          float* __restrict__ out, int bx, int by)
{
  __shared__ __align__(16) float sm[2 * 16 * 68];
  float* As = sm;
  float* Ws = sm + 16 * 68;
  const int tid = threadIdx.x;
  const int tx = tid & 15, ty = tid >> 4;
  const int g0 = bx * 64, r0 = by * 64;
  float acc[4][4];
#pragma unroll
  for (int i = 0; i < 4; ++i)
#pragma unroll
    for (int j = 0; j < 4; ++j) acc[i][j] = 0.0f;
  const int ks = tid & 15, rr = tid >> 4;
  for (int kt = 0; kt < 512; kt += 16) {
#pragma unroll
    for (int rep = 0; rep < 4; ++rep) {
      As[ks * 68 + rep * 16 + rr] = A[(size_t)(r0 + rep * 16 + rr) * 512 + kt + ks];
      Ws[ks * 68 + rep * 16 + rr] = W[(size_t)(g0 + rep * 16 + rr) * 513 + kt + ks];
    }
    __syncthreads();
#pragma unroll
    for (int k = 0; k < 16; ++k) {
      const float4 a4 = *(const float4*)&As[k * 68 + ty * 4];
      const float4 w4 = *(const float4*)&Ws[k * 68 + tx * 4];
      const float av[4] = {a4.x, a4.y, a4.z, a4.w};
      const float wv[4] = {w4.x, w4.y, w4.z, w4.w};
#pragma unroll
      for (int i = 0; i < 4; ++i)
#pragma unroll
        for (int j = 0; j < 4; ++j) acc[i][j] += av[i] * wv[j];
    }
    __syncthreads();
  }
#pragma unroll
  for (int i = 0; i < 4; ++i) {
    const int r = r0 + ty * 4 + i;
    float4 o;
    o.x = acc[i][0]; o.y = acc[i][1]; o.z = acc[i][2]; o.w = acc[i][3];
    *(float4*)&out[(size_t)r * 256 + g0 + tx * 4] = o;
  }
}

// ---- input projection body: X = embB @ WihB^T
__device__ void xproj_body(const unsigned short* __restrict__ embB,
                           const unsigned short* __restrict__ B,
                           float* __restrict__ out, int bx, int by)
{
  __shared__ __align__(16) unsigned short As[128 * 40];
  __shared__ __align__(16) unsigned short Bs[128 * 40];
  const int tid = threadIdx.x;
  const int g0 = bx * 128;
  const int r0 = by * 128;
  const int wave = tid >> 6, lane = tid & 63;
  const int wm = wave >> 1, wn = wave & 1;
  const int l15 = lane & 15, quad = lane >> 4;
  floatx4 acc[4][4];
#pragma unroll
  for (int mt = 0; mt < 4; ++mt)
#pragma unroll
    for (int nt = 0; nt < 4; ++nt) acc[mt][nt] = (floatx4){0.f, 0.f, 0.f, 0.f};
  for (int kt = 0; kt < 512; kt += 32) {
    __syncthreads();
#pragma unroll
    for (int p = 0; p < 2; ++p) {
      const int i = tid + p * 256;
      const int row = i >> 2, q = i & 3;
      *(uint4*)&As[row * 40 + q * 8] = *(const uint4*)&embB[(size_t)(r0 + row) * 512 + kt + q * 8];
      *(uint4*)&Bs[row * 40 + q * 8] = *(const uint4*)&B[(size_t)(g0 + row) * 512 + kt + q * 8];
    }
    __syncthreads();
    short8 af[4], bfr[4];
#pragma unroll
    for (int mt = 0; mt < 4; ++mt)
      af[mt] = *(const short8*)&As[(wm * 64 + mt * 16 + l15) * 40 + quad * 8];
#pragma unroll
    for (int nt = 0; nt < 4; ++nt)
      bfr[nt] = *(const short8*)&Bs[(wn * 64 + nt * 16 + l15) * 40 + quad * 8];
#pragma unroll
    for (int mt = 0; mt < 4; ++mt)
#pragma unroll
      for (int nt = 0; nt < 4; ++nt)
        acc[mt][nt] = __builtin_amdgcn_mfma_f32_16x16x32_bf16(af[mt], bfr[nt], acc[mt][nt], 0, 0, 0);
  }
#pragma unroll
  for (int nt = 0; nt < 4; ++nt) {
    const int col = g0 + wn * 64 + nt * 16 + l15;
#pragma unroll
    for (int mt = 0; mt < 4; ++mt)
#pragma unroll
      for (int i = 0; i < 4; ++i) {
        const int row = r0 + wm * 64 + mt * 16 + quad * 4 + i;
        out[(size_t)row * 2048 + col] = acc[mt][nt][i];
      }
  }
}

// ---- merged projection dispatch: blocks 0-31 E1-gemm, 32-159 xproj ----
__global__ __launch_bounds__(256)
void k_proj(const float* __restrict__ emb, const float* __restrict__ Wr1,
            float* __restrict__ E1,
            const unsigned short* __restrict__ embB,
            const unsigned short* __restrict__ WfB,
            const unsigned short* __restrict__ WbB,
            float* __restrict__ Xf, float* __restrict__ Xb)
{
  const int bid = blockIdx.x;
  if (bid < 32) {
    gemm_body(emb, Wr1, E1, bid & 3, bid >> 2);
  } else {
    const int idx = bid - 32;
    const int bz = idx >> 6, rem = idx & 63;
    xproj_body(embB, bz ? WbB : WfB, bz ? Xb : Xf, rem & 15, rem >> 4);
  }
}

// ---------------- big compose GEMM: gB[r,g] = bc[g] + U @ WcB^T ----------------
__global__ __launch_bounds__(256)
void k_mfma_gemm(const unsigned short* __restrict__ U, const unsigned short* __restrict__ WcB,
                 const float* __restrict__ bc, float* __restrict__ gB)
{
  __shared__ __align__(16) unsigned short As[128 * 40];
  __shared__ __align__(16) unsigned short Bs[64 * 40];
  const int bid = blockIdx.x;
  const int r0 = (bid / 80) * 128;
  const int g0 = (bid % 80) * 64;
  const int tid = threadIdx.x;
  const int wave = tid >> 6, lane = tid & 63;
  const int wm = wave >> 1, wn = wave & 1;
  const int l15 = lane & 15, quad = lane >> 4;
  floatx4 acc[4][2];
#pragma unroll
  for (int mf = 0; mf < 4; ++mf)
#pragma unroll
    for (int nt = 0; nt < 2; ++nt) acc[mf][nt] = (floatx4){0.f, 0.f, 0.f, 0.f};
  const int a_row = tid >> 2, a_q = tid & 3;
  for (int kt = 0; kt < K3; kt += 32) {
    __syncthreads();
#pragma unroll
    for (int p = 0; p < 2; ++p) {
      const int i = tid + p * 256;
      const int row = i >> 2, q = i & 3;
      *(uint4*)&As[row * 40 + q * 8] = *(const uint4*)&U[(size_t)(r0 + row) * K3 + kt + q * 8];
    }
    *(uint4*)&Bs[a_row * 40 + a_q * 8] = *(const uint4*)&WcB[(size_t)(g0 + a_row) * K3 + kt + a_q * 8];
    __syncthreads();
    short8 af[4], bfr[2];
#pragma unroll
    for (int mf = 0; mf < 4; ++mf)
      af[mf] = *(const short8*)&As[(wm * 64 + mf * 16 + l15) * 40 + quad * 8];
#pragma unroll
    for (int nt = 0; nt < 2; ++nt)
      bfr[nt] = *(const short8*)&Bs[(wn * 32 + nt * 16 + l15) * 40 + quad * 8];
#pragma unroll
    for (int mf = 0; mf < 4; ++mf)
#pragma unroll
      for (int nt = 0; nt < 2; ++nt)
        acc[mf][nt] = __builtin_amdgcn_mfma_f32_16x16x32_bf16(af[mf], bfr[nt], acc[mf][nt], 0, 0, 0);
  }
#pragma unroll
  for (int nt = 0; nt < 2; ++nt) {
    const int col = g0 + wn * 32 + nt * 16 + l15;
    const float bias = bc[col];
#pragma unroll
    for (int mf = 0; mf < 4; ++mf)
#pragma unroll
      for (int i = 0; i < 4; ++i) {
        const int row = r0 + wm * 64 + mf * 16 + quad * 4 + i;
        gB[(size_t)row * H5 + col] = acc[mf][nt][i] + bias;
      }
  }
}

// ---- scan body (blocks 0-63 of k_scansc) ----
__device__ void scan_body(const float* __restrict__ Xf, const float* __restrict__ Xb,
                          const unsigned short* __restrict__ WhfB,
                          const unsigned short* __restrict__ WhbB,
                          const float* __restrict__ bf, const float* __restrict__ bb,
                          const int* __restrict__ len,
                          unsigned short* __restrict__ hbB, float* __restrict__ cbuf,
                          float* __restrict__ hs, float* __restrict__ cs,
                          int* __restrict__ bar, int bid)
{
  const int dir = bid >> 5;
  const int hjt = bid & 31;
  const int tid = threadIdx.x;
  const int wave = tid >> 6, lane = tid & 63;
  const int l15 = lane & 15, quad = lane >> 4;
  const unsigned short* Wh = dir ? WhbB : WhfB;
  const float* bias = dir ? bb : bf;
  const float* X = dir ? Xb : Xf;
  int* myflags = &bar[528 + dir * 32];
  __shared__ float sg[4 * 16 * 17];
  const int jg = wave * 512 + hjt * 16 + l15;
  short8 wfr[16];
#pragma unroll
  for (int k8 = 0; k8 < 16; ++k8)
    wfr[k8] = *(const short8*)&Wh[(size_t)jg * 512 + k8 * 32 + quad * 8];
  const int bb_ = tid >> 4, j = tid & 15;
  const int hj = hjt * 16 + j;
  const int Lb = len[bb_];
  const float bi_i = bias[hj];
  const float bi_f = bias[512 + hj];
  const float bi_g = bias[1024 + hj];
  const float bi_o = bias[1536 + hj];
  for (int t = 0; t < SL; ++t) {
    const int pp = t & 1;
    const unsigned short* hp = hbB + (size_t)(dir * 2 + pp) * 8192;
    unsigned short* hn = hbB + (size_t)(dir * 2 + (pp ^ 1)) * 8192;
    const float* cp = cbuf + (size_t)(dir * 2 + pp) * 8192;
    float* cn = cbuf + (size_t)(dir * 2 + (pp ^ 1)) * 8192;
    int xidx = t;
    if (dir) xidx = (t < Lb) ? (Lb - 1 - t) : t;
    const float* xr = X + (size_t)(bb_ * SL + xidx) * 2048;
    const float x0 = xr[hj];
    const float x1 = xr[512 + hj];
    const float x2 = xr[1024 + hj];
    const float x3 = xr[1536 + hj];
    const float cprev = cp[bb_ * 512 + hj];
    short8 afr[16];
#pragma unroll
    for (int k8 = 0; k8 < 16; ++k8)
      asm volatile("global_load_dwordx4 %0, %1, off sc0 sc1"
                   : "=&v"(afr[k8])
                   : "v"(&hp[(size_t)l15 * 512 + k8 * 32 + quad * 8]));
    asm volatile("s_waitcnt vmcnt(0)" ::: "memory");
    __builtin_amdgcn_sched_barrier(0);
    floatx4 acc = (floatx4){0.f, 0.f, 0.f, 0.f};
#pragma unroll
    for (int k8 = 0; k8 < 16; ++k8)
      acc = __builtin_amdgcn_mfma_f32_16x16x32_bf16(afr[k8], wfr[k8], acc, 0, 0, 0);
#pragma unroll
    for (int i = 0; i < 4; ++i)
      sg[wave * 272 + (quad * 4 + i) * 17 + l15] = acc[i];
    __syncthreads();
    const float gi = sg[0 * 272 + bb_ * 17 + j] + x0 + bi_i;
    const float gf = sg[1 * 272 + bb_ * 17 + j] + x1 + bi_f;
    const float gg = sg[2 * 272 + bb_ * 17 + j] + x2 + bi_g;
    const float go = sg[3 * 272 + bb_ * 17 + j] + x3 + bi_o;
    const float cnew = sigf(gf) * cprev + sigf(gi) * tanhf(gg);
    const float hnew = sigf(go) * tanhf(cnew);
    cn[bb_ * 512 + hj] = cnew;
    const unsigned int hb16 = f2bf(hnew);
    asm volatile("global_store_short %0, %1, off sc0 sc1"
                 :: "v"(&hn[bb_ * 512 + hj]), "v"(hb16) : "memory");
    const int pos = dir ? xidx : t;
    const int col = dir ? (512 + hj) : hj;
    hs[(size_t)(bb_ * SL + pos) * 1024 + col] = hnew;
    cs[(size_t)(bb_ * SL + pos) * 1024 + col] = cnew;
    if (t != SL - 1) bar32(myflags, hjt, t + 1);
  }
}

// ---- score body (blocks 64+ of k_scansc) ----
__device__ void score_body(const float* __restrict__ E1, const float* __restrict__ Wr1,
                           const float* __restrict__ Wr2, const int* __restrict__ len,
                           int* __restrict__ ksplit, int b, int s)
{
  const int L = len[b];
  if (s + 2 > L) return;
  const int tid = threadIdx.x;
  __shared__ float e[32 * 257];
  __shared__ float w1p[256];
  __shared__ float w2s[256];
  __shared__ float red[32 * 8];
  __shared__ float sc[32];
  const int nrow = 32 - s;
  for (int i = tid; i < nrow * 256; i += 256) {
    const int rr = i >> 8, q = i & 255;
    e[rr * 257 + q] = E1[(size_t)(b * SL + s + rr) * 256 + q];
  }
  w1p[tid] = Wr1[tid * 513 + 512];
  w2s[tid] = Wr2[tid];
  __syncthreads();
  const int t_ = tid & 31, jg = tid >> 5;
  const int lmax = L - s;
  for (int l = 2; l <= lmax; ++l) {
    float part = 0.0f;
    if (t_ < l) {
      const float pos = 2.0f * (float)t_ / (float)l - 1.0f;
      const float* er = e + t_ * 257;
      for (int q = jg * 32; q < jg * 32 + 32; ++q) {
        const float v = er[q] + pos * w1p[q];
        part += fmaxf(v, 0.0f) * w2s[q];
      }
    }
    red[t_ * 8 + jg] = part;
    __syncthreads();
    if (jg == 0 && t_ < l) {
      float su = 0.0f;
      for (int q = 0; q < 8; ++q) su += red[t_ * 8 + q];
      sc[t_] = su;
    }
    __syncthreads();
    if (tid == 0) {
      int k = 0;
      float best = sc[0];
      for (int q = 1; q < l; ++q)
        if (sc[q] > best) { best = sc[q]; k = q; }
      ksplit[(b * 32 + s) * 33 + l] = k;
    }
    __syncthreads();
  }
}

// ---- merged scan + score dispatch: blocks 0-63 scan, 64-559 score ----
// Scan runs at 64 blocks (25% of CUs); score's throughput work fills the
// idle CUs -> score time disappears from the critical path.
__global__ __launch_bounds__(256)
void k_scansc(const float* Xf, const float* Xb,
              const unsigned short* WhfB, const unsigned short* WhbB,
              const float* bf, const float* bb, const int* len,
              unsigned short* hbB, float* cbuf, float* hs, float* cs, int* bar,
              const float* E1, const float* Wr1, const float* Wr2, int* ksplit)
{
  const int bid = blockIdx.x;
  if (bid < 64) {
    scan_body(Xf, Xb, WhfB, WhbB, bf, bb, len, hbB, cbuf, hs, cs, bar, bid);
  } else {
    const int idx = bid - 64;
    score_body(E1, Wr1, Wr2, len, ksplit, idx / 31, idx % 31);
  }
}

// ---------------- DFS walk using precomputed splits ----------------
__global__ __launch_bounds__(64)
void k_walk(const int* __restrict__ ksplit, const int* __restrict__ len,
            int* __restrict__ meta)
{
  const int b = blockIdx.x;
  const int tid = threadIdx.x;
  __shared__ int ks[32 * 33];
  __shared__ int stk[96];
  for (int i = tid; i < 32 * 33; i += 64) ks[i] = ksplit[b * 1056 + i];
  __syncthreads();
  if (tid != 0) return;
  int* own = meta;
  int* lt = meta + 512;
  int* li = meta + 1024;
  int* rt = meta + 1536;
  int* ri = meta + 2048;
  int* dep = meta + 2560;
  int* nn = meta + 3072;
  int* dcnt = meta + 3088;
  int* lcnt = meta + 3120;
  int* dlist = meta + 3152;
  int* llist = meta + 19536;
  int sp = 0, nn_ = 1;
  stk[0] = 0; stk[1] = len[b]; stk[2] = 0;
  sp = 1;
  while (sp > 0) {
    sp--;
    const int s = stk[sp * 3], eN = stk[sp * 3 + 1], nid = stk[sp * 3 + 2];
    const int l = eN - s;
    const int k = ks[s * 33 + l];
    const int m = b * 32 + nid;
    own[m] = s + k;
    if (k == 0) { lt[m] = 0; li[m] = 0; }
    else if (k == 1) { lt[m] = 1; li[m] = s; }
    else {
      const int id = nn_++;
      lt[m] = 2; li[m] = id;
      stk[sp * 3] = s; stk[sp * 3 + 1] = s + k; stk[sp * 3 + 2] = id; sp++;
    }
    const int rl = l - k - 1;
    if (rl == 0) { rt[m] = 0; ri[m] = 0; }
    else if (rl == 1) { rt[m] = 1; ri[m] = s + k + 1; }
    else {
      const int id = nn_++;
      rt[m] = 2; ri[m] = id;
      stk[sp * 3] = s + k + 1; stk[sp * 3 + 1] = eN; stk[sp * 3 + 2] = id; sp++;
    }
  }
  nn[b] = nn_;
  for (int i = nn_ - 1; i >= 0; --i) {
    const int m = b * 32 + i;
    int d = 1;
    if (lt[m] == 2) d = max(d, dep[b * 32 + li[m]] + 1);
    if (rt[m] == 2) d = max(d, dep[b * 32 + ri[m]] + 1);
    dep[m] = d;
  }
  for (int i = 0; i < nn_; ++i) {
    const int m = b * 32 + i;
    const int r = dep[m];
    const int idx = atomicAdd(&dcnt[r], 1);
    dlist[r * 512 + idx] = m;
    if (lt[m] == 2 || rt[m] == 2) {
      const int lx = atomicAdd(&lcnt[r], 1);
      llist[r * 512 + lx] = m;
    }
  }
}

// ---------------- build U (bf16) = [hl_leaf|0 , hr_leaf|0 , hx] per node ----------------
__global__ __launch_bounds__(256)
void k_ubuild(const float* __restrict__ hs, const int* __restrict__ meta,
              unsigned short* __restrict__ U)
{
  const int id = blockIdx.x, b = blockIdx.y;
  const int tid = threadIdx.x;
  const int* own = meta;
  const int* lt = meta + 512;
  const int* li = meta + 1024;
  const int* rt = meta + 1536;
  const int* ri = meta + 2048;
  const int* nn = meta + 3072;
  const int m = b * 32 + id;
  unsigned short* u = U + (size_t)m * K3;
  if (id >= nn[b]) {
    for (int i = tid; i < K3; i += 256) u[i] = 0;
    return;
  }
  const float* hl = (lt[m] == 1) ? hs + (size_t)(b * 32 + li[m]) * 1024 : nullptr;
  const float* hr = (rt[m] == 1) ? hs + (size_t)(b * 32 + ri[m]) * 1024 : nullptr;
  const float* hx = hs + (size_t)(b * 32 + own[m]) * 1024;
  for (int i = tid; i < 1024; i += 256) {
    u[i] = hl ? f2bf(hl[i]) : 0;
    u[1024 + i] = hr ? f2bf(hr[i]) : 0;
    u[2048 + i] = f2bf(hx[i]);
  }
}

// ---------------- fused tree rounds: hidden-index-partitioned ---------------
// grid 512: block owns hidden cols j0=2*bid, j0+1 and all five gate rows.
// Wc fragments in 64 VGPRs (round-invariant). Cross-block data = nodehb only
// (sc0sc1). One monitor barrier per round. LDS padded +1 col (bank conflicts).
__global__ __launch_bounds__(256, 2)
void k_rounds(const unsigned short* __restrict__ WcB, const int* __restrict__ meta,
              unsigned short* __restrict__ nodehb,
              const float* __restrict__ gB, const float* __restrict__ cs,
              float* __restrict__ nodec,
              float* __restrict__ out, int* __restrict__ bar,
              const unsigned short* __restrict__ zpad)
{
  const int* lt = meta + 512;
  const int* li = meta + 1024;
  const int* rt = meta + 1536;
  const int* ri = meta + 2048;
  const int* dcnt = meta + 3088;
  const int* dlist = meta + 3152;
  __shared__ float scratch[4][16][17];   // padded: kills 4-way bank conflict
  __shared__ float gates[16][17];
  const int tid = threadIdx.x;
  const int bid = blockIdx.x;
  const int wave = tid >> 6, lane = tid & 63;
  const int l15 = lane & 15, quad = lane >> 4;
  const int j0 = bid * 2;
  const int cc = (l15 < 10) ? l15 : l15 - 10;
  const size_t wrow = (size_t)((cc >> 1) * 1024 + j0 + (cc & 1)) * K3;
  const int kbase = wave * 256 + quad * 8;
  short8 wreg[16];
#pragma unroll
  for (int i = 0; i < 8; ++i) {
    wreg[i]     = *(const short8*)&WcB[wrow + kbase + i * 32];
    wreg[8 + i] = *(const short8*)&WcB[wrow + 1024 + kbase + i * 32];
  }
  const int rnd = tid >> 4, rc = tid & 15;
  int bgen = 0;
  for (int r = 1; r <= 31; ++r) {
    const int cnt = dcnt[r];
    if (cnt == 0) break;
    if (r >= 2) { ++bgen; bar_rounds(bar, &bar[512], bid, bgen); }
    for (int c0 = 0; c0 < cnt; c0 += 16) {
      float gBv = 0.0f;
      if (rc < 10 && c0 + rnd < cnt) {
        const int nodeP = dlist[r * 512 + c0 + rnd];
        gBv = gB[(size_t)nodeP * H5 + (rc >> 1) * 1024 + j0 + (rc & 1)];
      }
      const int ma = c0 + l15;
      const unsigned short* pl = zpad;
      const unsigned short* pr = zpad;
      if (ma < cnt) {
        const int node = dlist[r * 512 + ma];
        const int base = node & ~31;
        if (lt[node] == 2) pl = nodehb + (size_t)(base + li[node]) * 1024;
        if (rt[node] == 2) pr = nodehb + (size_t)(base + ri[node]) * 1024;
      }
      short8 al[8], ar[8];
#pragma unroll
      for (int i = 0; i < 8; ++i)
        asm volatile("global_load_dwordx4 %0, %1, off sc0 sc1"
                     : "=&v"(al[i]) : "v"(pl + kbase + i * 32));
#pragma unroll
      for (int i = 0; i < 8; ++i)
        asm volatile("global_load_dwordx4 %0, %1, off sc0 sc1"
                     : "=&v"(ar[i]) : "v"(pr + kbase + i * 32));
      floatx4 acc = (floatx4){0.f, 0.f, 0.f, 0.f};
      asm volatile("s_waitcnt vmcnt(8)" ::: "memory");
      __builtin_amdgcn_sched_barrier(0);
#pragma unroll
      for (int ks = 0; ks < 8; ++ks)
        acc = __builtin_amdgcn_mfma_f32_16x16x32_bf16(al[ks], wreg[ks], acc, 0, 0, 0);
      asm volatile("s_waitcnt vmcnt(0)" ::: "memory");
      __builtin_amdgcn_sched_barrier(0);
#pragma unroll
      for (int ks = 0; ks < 8; ++ks)
        acc = __builtin_amdgcn_mfma_f32_16x16x32_bf16(ar[ks], wreg[8 + ks], acc, 0, 0, 0);
      __syncthreads();
#pragma unroll
      for (int i = 0; i < 4; ++i)
        scratch[wave][quad * 4 + i][l15] = acc[i];
      __syncthreads();
      if (rc < 10)
        gates[rnd][rc] = gBv + scratch[0][rnd][rc] + scratch[1][rnd][rc]
                             + scratch[2][rnd][rc] + scratch[3][rnd][rc];
      __syncthreads();
      if (tid < 16) {
        const int mc = c0 + tid;
        if (mc < cnt) {
          const int node = dlist[r * 512 + mc];
          const int base = node & ~31;
          const int ltv = lt[node], rtv = rt[node];
          const float* clp = (ltv == 2) ? &nodec[(size_t)(base + li[node]) * 1024]
                           : (ltv == 1) ? &cs[(size_t)(base + li[node]) * 1024] : nullptr;
          const float* crp = (rtv == 2) ? &nodec[(size_t)(base + ri[node]) * 1024]
                           : (rtv == 1) ? &cs[(size_t)(base + ri[node]) * 1024] : nullptr;
          unsigned int pk = 0;
#pragma unroll
          for (int jj = 0; jj < 2; ++jj) {
            const int j = j0 + jj;
            const float gi  = gates[tid][0 + jj];
            const float gfl = gates[tid][2 + jj];
            const float gfr = gates[tid][4 + jj];
            const float gu  = gates[tid][6 + jj];
            const float go  = gates[tid][8 + jj];
            const float cl = clp ? clp[j] : 0.0f;
            const float cr = crp ? crp[j] : 0.0f;
            const float c_ = sigf(gfl) * cl + sigf(gfr) * cr + sigf(gi) * tanhf(gu);
            const float h  = sigf(go) * tanhf(c_);
            nodec[(size_t)node * 1024 + j] = c_;
            pk |= ((unsigned int)f2bf(h)) << (16 * jj);
            if ((node & 31) == 0) {
              const int b = node >> 5;
              out[b * 1024 + j] = h;
              out[16384 + b * 1024 + j] = c_;
            }
          }
          asm volatile("global_store_dword %0, %1, off sc0 sc1"
                       :: "v"(nodehb + (size_t)node * 1024 + j0), "v"(pk)
                       : "memory");
        }
      }
    }
  }
}

extern "C" void kernel_launch(void* const* d_in, const int* in_sizes, int n_in,
                              void* d_out, int out_size, void* d_ws, size_t ws_size,
                              hipStream_t stream) {
  const float* emb = (const float*)d_in[0];
  const int* len = (const int*)d_in[1];
  const float* Wihf = (const float*)d_in[2];
  const float* Whhf = (const float*)d_in[3];
  const float* bf = (const float*)d_in[4];
  const float* Wihb = (const float*)d_in[5];
  const float* Whhb = (const float*)d_in[6];
  const float* bb = (const float*)d_in[7];
  const float* Wr1 = (const float*)d_in[8];
  const float* Wr2 = (const float*)d_in[9];
  const float* Wc = (const float*)d_in[10];
  const float* bc = (const float*)d_in[11];
  float* out = (float*)d_out;

  float* ws = (float*)d_ws;
  float* Xf = ws;                                         // 1048576 f
  float* Xb = Xf + 1048576;                               // 1048576 f
  float* hs = Xb + 1048576;                               // 524288 f
  float* cs = hs + 524288;                                // 524288 f
  float* E1 = cs + 524288;                                // 131072 f
  unsigned short* U = (unsigned short*)(E1 + 131072);     // 786432 f
  float* gB = (float*)U + 786432;                         // 2621440 f
  float* nodeh = gB + 2621440;                            // 524288 f (unused)
  float* nodec = nodeh + 524288;                          // 524288 f
  unsigned short* nodehb = (unsigned short*)(nodec + 524288);     // 262144 f
  float* cbuf = (float*)nodehb + 262144;                  // 32768 f
  unsigned short* hbB = (unsigned short*)(cbuf + 32768);  // 16384 f
  unsigned short* WcB = (unsigned short*)((float*)hbB + 16384);   // 7864320 f
  unsigned short* WihfB = WcB + 15728640;                 // 1048576 sh
  unsigned short* WihbB = WihfB + 1048576;
  unsigned short* WhhfB = WihbB + 1048576;
  unsigned short* WhhbB = WhhfB + 1048576;
  unsigned short* embB = WhhbB + 1048576;                 // 262144 sh
  int* meta = (int*)(embB + 262144);                      // ~36K ints
  int* ksplit = meta + 36096;                             // 16*1056 ints
  int* bar = ksplit + 16896;                              // 1024 ints barrier state
  unsigned short* zpad = (unsigned short*)(bar + 1024);   // 1024 sh zeroed
  // bar layout: [0..511] rounds flags, [512] rounds gen,
  //             [528..559] scan flags dir0, [560..591] scan flags dir1

  // merged zero: cbuf + depth counters + barrier/zpad state (1 dispatch)
  k_zero3<<<128, 256, 0, stream>>>(cbuf, 49152, (float*)(meta + 3088), 64,
                                   (float*)bar, 1536);
  // bf16 conversions
  k_conv6<<<dim3(1920, 6), 256, 0, stream>>>(
      Wc, WcB, 15728640, Wihf, WihfB, 1048576, Wihb, WihbB, 1048576,
      Whhf, WhhfB, 1048576, Whhb, WhhbB, 1048576, emb, embB, 262144);
  // merged E1 rank projection + input projections (1 dispatch)
  k_proj<<<160, 256, 0, stream>>>(emb, Wr1, E1, embB, WihfB, WihbB, Xf, Xb);
  // merged recurrent scan + split scoring (scan latency hides score work)
  k_scansc<<<560, 256, 0, stream>>>(Xf, Xb, WhhfB, WhhbB, bf, bb, len, hbB,
                                    cbuf, hs, cs, bar, E1, Wr1, Wr2, ksplit);
  // DFS walk (cheap)
  k_walk<<<16, 64, 0, stream>>>(ksplit, len, meta);
  // precomputable part of every compose
  k_ubuild<<<dim3(32, 16), 256, 0, stream>>>(hs, meta, U);
  k_mfma_gemm<<<320, 256, 0, stream>>>(U, WcB, bc, gB);
  // fused tree rounds (512 blocks, 1 monitor barrier/round)
  k_rounds<<<512, 256, 0, stream>>>(WcB, meta, nodehb, gB, cs,
                                    nodec, out, bar, zpad);
}

// Round 14
// 510.067 us; speedup vs baseline: 1.2003x; 1.0784x over previous
//
#include <hip/hip_runtime.h>
#include <math.h>

#define NB 16
#define SL 32
#define H5 5120
#define K3 3072

typedef __attribute__((ext_vector_type(8))) short short8;
typedef __attribute__((ext_vector_type(4))) float floatx4;
typedef __attribute__((ext_vector_type(4))) int intx4;

__device__ __forceinline__ float sigf(float x) { return 1.0f / (1.0f + expf(-x)); }

__device__ __forceinline__ unsigned short f2bf(float x) {
  union { float f; unsigned int u; } v;
  v.f = x;
  unsigned int r = v.u + 0x7FFFu + ((v.u >> 16) & 1u);
  return (unsigned short)(r >> 16);
}

// ---- barrier variants (hybrid of best-measured per scale) ------------------
// 32-block: direct-poll all-to-all (r12: best for scan, 1 L3 hop).
__device__ __forceinline__ void bar32(int* flags, int idx, int mygen) {
  asm volatile("s_waitcnt vmcnt(0)" ::: "memory");
  __syncthreads();
  const int tid = threadIdx.x;
  if (tid == 0)
    __hip_atomic_store(&flags[idx], mygen, __ATOMIC_RELAXED,
                       __HIP_MEMORY_SCOPE_AGENT);
  if (tid < 64) {
    const int off = (tid & 7) * 4;
    int ok;
    do {
      intx4 f;
      asm volatile("global_load_dwordx4 %0, %1, off sc0 sc1\n\t"
                   "s_waitcnt vmcnt(0)"
                   : "=&v"(f) : "v"(flags + off) : "memory");
      ok = (f.x >= mygen) & (f.y >= mygen) & (f.z >= mygen) & (f.w >= mygen);
    } while (__all(ok) == 0);
  }
  __syncthreads();
}

// 512-block: monitor (r11: best for rounds — single poller avoids 512-way
// poll contention; r12's direct-poll regressed k_rounds).
__device__ __forceinline__ void bar_rounds(int* flags, int* gen, int bid, int mygen) {
  asm volatile("s_waitcnt vmcnt(0)" ::: "memory");
  __syncthreads();
  const int tid = threadIdx.x;
  if (tid < 64) {
    if (tid == 0)
      __hip_atomic_store(&flags[bid], mygen, __ATOMIC_RELAXED,
                         __HIP_MEMORY_SCOPE_AGENT);
    if (bid == 0) {
      int ok;
      do {
        intx4 f0, f1;
        asm volatile("global_load_dwordx4 %0, %2, off sc0 sc1\n\t"
                     "global_load_dwordx4 %1, %3, off sc0 sc1\n\t"
                     "s_waitcnt vmcnt(0)"
                     : "=&v"(f0), "=&v"(f1)
                     : "v"(flags + tid * 8), "v"(flags + tid * 8 + 4)
                     : "memory");
        ok = (f0.x >= mygen) & (f0.y >= mygen) & (f0.z >= mygen) & (f0.w >= mygen)
           & (f1.x >= mygen) & (f1.y >= mygen) & (f1.z >= mygen) & (f1.w >= mygen);
      } while (__all(ok) == 0);
      if (tid == 0)
        __hip_atomic_store(gen, mygen, __ATOMIC_RELAXED,
                           __HIP_MEMORY_SCOPE_AGENT);
    } else if (tid == 0) {
      while (__hip_atomic_load(gen, __ATOMIC_RELAXED,
                               __HIP_MEMORY_SCOPE_AGENT) < mygen)
        __builtin_amdgcn_s_sleep(2);
    }
  }
  __syncthreads();
}

// meta layout (ints):
//  own 0, lt 512, li 1024, rt 1536, ri 2048, dep 2560, nn 3072(16),
//  dcnt 3088(32), lcnt 3120(32), dlist 3152(32*512), llist 19536(32*512)

// ---------------- merged zero (3 segments, one dispatch) ----------------
__global__ void k_zero3(float* a, int na, float* b, int nb_, float* c, int nc) {
  const int stride = gridDim.x * blockDim.x;
  int i = blockIdx.x * blockDim.x + threadIdx.x;
  for (int k = i; k < na; k += stride) a[k] = 0.0f;
  for (int k = i; k < nb_; k += stride) b[k] = 0.0f;
  for (int k = i; k < nc; k += stride) c[k] = 0.0f;
}

// ---------------- batch f32 -> bf16 conversion (5 small segments) -----------
// (Wc conversion moved into k_scansc — hidden under the scan's idle CUs.)
__global__ void k_conv5(const float* s0, unsigned short* d0, int n0,
                        const float* s1, unsigned short* d1, int n1,
                        const float* s2, unsigned short* d2, int n2,
                        const float* s3, unsigned short* d3, int n3,
                        const float* s4, unsigned short* d4, int n4)
{
  const float* s; unsigned short* d; int n;
  switch (blockIdx.y) {
    case 0: s = s0; d = d0; n = n0; break;
    case 1: s = s1; d = d1; n = n1; break;
    case 2: s = s2; d = d2; n = n2; break;
    case 3: s = s3; d = d3; n = n3; break;
    default: s = s4; d = d4; n = n4; break;
  }
  const int nf4 = n >> 2;
  for (int i = blockIdx.x * blockDim.x + threadIdx.x; i < nf4; i += gridDim.x * blockDim.x) {
    const float4 v = *(const float4*)&s[i * 4];
    ushort4 o;
    o.x = f2bf(v.x); o.y = f2bf(v.y); o.z = f2bf(v.z); o.w = f2bf(v.w);
    *(ushort4*)&d[i * 4] = o;
  }
}

// ---- E1 gemm body (f32): out[r,g] = sum_k A[r,k]*W[g,k]; lda=512 ldw=513
__device__ void gemm_body(const float* __restrict__ A, const float* __restrict__ W,
                          float* __restrict__ out, int bx, int by)
{
  __shared__ __align__(16) float sm[2 * 16 * 68];
  float* As = sm;
  float* Ws = sm + 16 * 68;
  const int tid = threadIdx.x;
  const int tx = tid & 15, ty = tid >> 4;
  const int g0 = bx * 64, r0 = by * 64;
  float acc[4][4];
#pragma unroll
  for (int i = 0; i < 4; ++i)
#pragma unroll
    for (int j = 0; j < 4; ++j) acc[i][j] = 0.0f;
  const int ks = tid & 15, rr = tid >> 4;
  for (int kt = 0; kt < 512; kt += 16) {
#pragma unroll
    for (int rep = 0; rep < 4; ++rep) {
      As[ks * 68 + rep * 16 + rr] = A[(size_t)(r0 + rep * 16 + rr) * 512 + kt + ks];
      Ws[ks * 68 + rep * 16 + rr] = W[(size_t)(g0 + rep * 16 + rr) * 513 + kt + ks];
    }
    __syncthreads();
#pragma unroll
    for (int k = 0; k < 16; ++k) {
      const float4 a4 = *(const float4*)&As[k * 68 + ty * 4];
      const float4 w4 = *(const float4*)&Ws[k * 68 + tx * 4];
      const float av[4] = {a4.x, a4.y, a4.z, a4.w};
      const float wv[4] = {w4.x, w4.y, w4.z, w4.w};
#pragma unroll
      for (int i = 0; i < 4; ++i)
#pragma unroll
        for (int j = 0; j < 4; ++j) acc[i][j] += av[i] * wv[j];
    }
    __syncthreads();
  }
#pragma unroll
  for (int i = 0; i < 4; ++i) {
    const int r = r0 + ty * 4 + i;
    float4 o;
    o.x = acc[i][0]; o.y = acc[i][1]; o.z = acc[i][2]; o.w = acc[i][3];
    *(float4*)&out[(size_t)r * 256 + g0 + tx * 4] = o;
  }
}

// ---- input projection body: X = embB @ WihB^T
__device__ void xproj_body(const unsigned short* __restrict__ embB,
                           const unsigned short* __restrict__ B,
                           float* __restrict__ out, int bx, int by)
{
  __shared__ __align__(16) unsigned short As[128 * 40];
  __shared__ __align__(16) unsigned short Bs[128 * 40];
  const int tid = threadIdx.x;
  const int g0 = bx * 128;
  const int r0 = by * 128;
  const int wave = tid >> 6, lane = tid & 63;
  const int wm = wave >> 1, wn = wave & 1;
  const int l15 = lane & 15, quad = lane >> 4;
  floatx4 acc[4][4];
#pragma unroll
  for (int mt = 0; mt < 4; ++mt)
#pragma unroll
    for (int nt = 0; nt < 4; ++nt) acc[mt][nt] = (floatx4){0.f, 0.f, 0.f, 0.f};
  for (int kt = 0; kt < 512; kt += 32) {
    __syncthreads();
#pragma unroll
    for (int p = 0; p < 2; ++p) {
      const int i = tid + p * 256;
      const int row = i >> 2, q = i & 3;
      *(uint4*)&As[row * 40 + q * 8] = *(const uint4*)&embB[(size_t)(r0 + row) * 512 + kt + q * 8];
      *(uint4*)&Bs[row * 40 + q * 8] = *(const uint4*)&B[(size_t)(g0 + row) * 512 + kt + q * 8];
    }
    __syncthreads();
    short8 af[4], bfr[4];
#pragma unroll
    for (int mt = 0; mt < 4; ++mt)
      af[mt] = *(const short8*)&As[(wm * 64 + mt * 16 + l15) * 40 + quad * 8];
#pragma unroll
    for (int nt = 0; nt < 4; ++nt)
      bfr[nt] = *(const short8*)&Bs[(wn * 64 + nt * 16 + l15) * 40 + quad * 8];
#pragma unroll
    for (int mt = 0; mt < 4; ++mt)
#pragma unroll
      for (int nt = 0; nt < 4; ++nt)
        acc[mt][nt] = __builtin_amdgcn_mfma_f32_16x16x32_bf16(af[mt], bfr[nt], acc[mt][nt], 0, 0, 0);
  }
#pragma unroll
  for (int nt = 0; nt < 4; ++nt) {
    const int col = g0 + wn * 64 + nt * 16 + l15;
#pragma unroll
    for (int mt = 0; mt < 4; ++mt)
#pragma unroll
      for (int i = 0; i < 4; ++i) {
        const int row = r0 + wm * 64 + mt * 16 + quad * 4 + i;
        out[(size_t)row * 2048 + col] = acc[mt][nt][i];
      }
  }
}

// ---- merged projection dispatch: blocks 0-31 E1-gemm, 32-159 xproj ----
__global__ __launch_bounds__(256)
void k_proj(const float* __restrict__ emb, const float* __restrict__ Wr1,
            float* __restrict__ E1,
            const unsigned short* __restrict__ embB,
            const unsigned short* __restrict__ WfB,
            const unsigned short* __restrict__ WbB,
            float* __restrict__ Xf, float* __restrict__ Xb)
{
  const int bid = blockIdx.x;
  if (bid < 32) {
    gemm_body(emb, Wr1, E1, bid & 3, bid >> 2);
  } else {
    const int idx = bid - 32;
    const int bz = idx >> 6, rem = idx & 63;
    xproj_body(embB, bz ? WbB : WfB, bz ? Xb : Xf, rem & 15, rem >> 4);
  }
}

// ---------------- big compose GEMM: gB[r,g] = bc[g] + U @ WcB^T ----------------
__global__ __launch_bounds__(256)
void k_mfma_gemm(const unsigned short* __restrict__ U, const unsigned short* __restrict__ WcB,
                 const float* __restrict__ bc, float* __restrict__ gB)
{
  __shared__ __align__(16) unsigned short As[128 * 40];
  __shared__ __align__(16) unsigned short Bs[64 * 40];
  const int bid = blockIdx.x;
  const int r0 = (bid / 80) * 128;
  const int g0 = (bid % 80) * 64;
  const int tid = threadIdx.x;
  const int wave = tid >> 6, lane = tid & 63;
  const int wm = wave >> 1, wn = wave & 1;
  const int l15 = lane & 15, quad = lane >> 4;
  floatx4 acc[4][2];
#pragma unroll
  for (int mf = 0; mf < 4; ++mf)
#pragma unroll
    for (int nt = 0; nt < 2; ++nt) acc[mf][nt] = (floatx4){0.f, 0.f, 0.f, 0.f};
  const int a_row = tid >> 2, a_q = tid & 3;
  for (int kt = 0; kt < K3; kt += 32) {
    __syncthreads();
#pragma unroll
    for (int p = 0; p < 2; ++p) {
      const int i = tid + p * 256;
      const int row = i >> 2, q = i & 3;
      *(uint4*)&As[row * 40 + q * 8] = *(const uint4*)&U[(size_t)(r0 + row) * K3 + kt + q * 8];
    }
    *(uint4*)&Bs[a_row * 40 + a_q * 8] = *(const uint4*)&WcB[(size_t)(g0 + a_row) * K3 + kt + a_q * 8];
    __syncthreads();
    short8 af[4], bfr[2];
#pragma unroll
    for (int mf = 0; mf < 4; ++mf)
      af[mf] = *(const short8*)&As[(wm * 64 + mf * 16 + l15) * 40 + quad * 8];
#pragma unroll
    for (int nt = 0; nt < 2; ++nt)
      bfr[nt] = *(const short8*)&Bs[(wn * 32 + nt * 16 + l15) * 40 + quad * 8];
#pragma unroll
    for (int mf = 0; mf < 4; ++mf)
#pragma unroll
      for (int nt = 0; nt < 2; ++nt)
        acc[mf][nt] = __builtin_amdgcn_mfma_f32_16x16x32_bf16(af[mf], bfr[nt], acc[mf][nt], 0, 0, 0);
  }
#pragma unroll
  for (int nt = 0; nt < 2; ++nt) {
    const int col = g0 + wn * 32 + nt * 16 + l15;
    const float bias = bc[col];
#pragma unroll
    for (int mf = 0; mf < 4; ++mf)
#pragma unroll
      for (int i = 0; i < 4; ++i) {
        const int row = r0 + wm * 64 + mf * 16 + quad * 4 + i;
        gB[(size_t)row * H5 + col] = acc[mf][nt][i] + bias;
      }
  }
}

// ---- scan body (blocks 0-63 of k_scansc) ----
__device__ void scan_body(const float* __restrict__ Xf, const float* __restrict__ Xb,
                          const unsigned short* __restrict__ WhfB,
                          const unsigned short* __restrict__ WhbB,
                          const float* __restrict__ bf, const float* __restrict__ bb,
                          const int* __restrict__ len,
                          unsigned short* __restrict__ hbB, float* __restrict__ cbuf,
                          float* __restrict__ hs, float* __restrict__ cs,
                          int* __restrict__ bar, int bid)
{
  const int dir = bid >> 5;
  const int hjt = bid & 31;
  const int tid = threadIdx.x;
  const int wave = tid >> 6, lane = tid & 63;
  const int l15 = lane & 15, quad = lane >> 4;
  const unsigned short* Wh = dir ? WhbB : WhfB;
  const float* bias = dir ? bb : bf;
  const float* X = dir ? Xb : Xf;
  int* myflags = &bar[528 + dir * 32];
  __shared__ float sg[4 * 16 * 17];
  const int jg = wave * 512 + hjt * 16 + l15;
  short8 wfr[16];
#pragma unroll
  for (int k8 = 0; k8 < 16; ++k8)
    wfr[k8] = *(const short8*)&Wh[(size_t)jg * 512 + k8 * 32 + quad * 8];
  const int bb_ = tid >> 4, j = tid & 15;
  const int hj = hjt * 16 + j;
  const int Lb = len[bb_];
  const float bi_i = bias[hj];
  const float bi_f = bias[512 + hj];
  const float bi_g = bias[1024 + hj];
  const float bi_o = bias[1536 + hj];
  for (int t = 0; t < SL; ++t) {
    const int pp = t & 1;
    const unsigned short* hp = hbB + (size_t)(dir * 2 + pp) * 8192;
    unsigned short* hn = hbB + (size_t)(dir * 2 + (pp ^ 1)) * 8192;
    const float* cp = cbuf + (size_t)(dir * 2 + pp) * 8192;
    float* cn = cbuf + (size_t)(dir * 2 + (pp ^ 1)) * 8192;
    int xidx = t;
    if (dir) xidx = (t < Lb) ? (Lb - 1 - t) : t;
    const float* xr = X + (size_t)(bb_ * SL + xidx) * 2048;
    const float x0 = xr[hj];
    const float x1 = xr[512 + hj];
    const float x2 = xr[1024 + hj];
    const float x3 = xr[1536 + hj];
    const float cprev = cp[bb_ * 512 + hj];
    short8 afr[16];
#pragma unroll
    for (int k8 = 0; k8 < 16; ++k8)
      asm volatile("global_load_dwordx4 %0, %1, off sc0 sc1"
                   : "=&v"(afr[k8])
                   : "v"(&hp[(size_t)l15 * 512 + k8 * 32 + quad * 8]));
    asm volatile("s_waitcnt vmcnt(0)" ::: "memory");
    __builtin_amdgcn_sched_barrier(0);
    floatx4 acc = (floatx4){0.f, 0.f, 0.f, 0.f};
#pragma unroll
    for (int k8 = 0; k8 < 16; ++k8)
      acc = __builtin_amdgcn_mfma_f32_16x16x32_bf16(afr[k8], wfr[k8], acc, 0, 0, 0);
#pragma unroll
    for (int i = 0; i < 4; ++i)
      sg[wave * 272 + (quad * 4 + i) * 17 + l15] = acc[i];
    __syncthreads();
    const float gi = sg[0 * 272 + bb_ * 17 + j] + x0 + bi_i;
    const float gf = sg[1 * 272 + bb_ * 17 + j] + x1 + bi_f;
    const float gg = sg[2 * 272 + bb_ * 17 + j] + x2 + bi_g;
    const float go = sg[3 * 272 + bb_ * 17 + j] + x3 + bi_o;
    const float cnew = sigf(gf) * cprev + sigf(gi) * tanhf(gg);
    const float hnew = sigf(go) * tanhf(cnew);
    cn[bb_ * 512 + hj] = cnew;
    const unsigned int hb16 = f2bf(hnew);
    asm volatile("global_store_short %0, %1, off sc0 sc1"
                 :: "v"(&hn[bb_ * 512 + hj]), "v"(hb16) : "memory");
    const int pos = dir ? xidx : t;
    const int col = dir ? (512 + hj) : hj;
    hs[(size_t)(bb_ * SL + pos) * 1024 + col] = hnew;
    cs[(size_t)(bb_ * SL + pos) * 1024 + col] = cnew;
    if (t != SL - 1) bar32(myflags, hjt, t + 1);
  }
}

// ---- score body: ksplit stores sc-coherent; ALWAYS sets completion flag ----
__device__ void score_body(const float* __restrict__ E1, const float* __restrict__ Wr1,
                           const float* __restrict__ Wr2, const int* __restrict__ len,
                           int* __restrict__ ksplit, int* __restrict__ sflag,
                           int b, int s)
{
  const int tid = threadIdx.x;
  const int L = len[b];
  if (s + 2 <= L) {
    __shared__ float e[32 * 257];
    __shared__ float w1p[256];
    __shared__ float w2s[256];
    __shared__ float red[32 * 8];
    __shared__ float sc[32];
    const int nrow = 32 - s;
    for (int i = tid; i < nrow * 256; i += 256) {
      const int rr = i >> 8, q = i & 255;
      e[rr * 257 + q] = E1[(size_t)(b * SL + s + rr) * 256 + q];
    }
    w1p[tid] = Wr1[tid * 513 + 512];
    w2s[tid] = Wr2[tid];
    __syncthreads();
    const int t_ = tid & 31, jg = tid >> 5;
    const int lmax = L - s;
    for (int l = 2; l <= lmax; ++l) {
      float part = 0.0f;
      if (t_ < l) {
        const float pos = 2.0f * (float)t_ / (float)l - 1.0f;
        const float* er = e + t_ * 257;
        for (int q = jg * 32; q < jg * 32 + 32; ++q) {
          const float v = er[q] + pos * w1p[q];
          part += fmaxf(v, 0.0f) * w2s[q];
        }
      }
      red[t_ * 8 + jg] = part;
      __syncthreads();
      if (jg == 0 && t_ < l) {
        float su = 0.0f;
        for (int q = 0; q < 8; ++q) su += red[t_ * 8 + q];
        sc[t_] = su;
      }
      __syncthreads();
      if (tid == 0) {
        int k = 0;
        float best = sc[0];
        for (int q = 1; q < l; ++q)
          if (sc[q] > best) { best = sc[q]; k = q; }
        __hip_atomic_store(&ksplit[(b * 32 + s) * 33 + l], k,
                           __ATOMIC_RELAXED, __HIP_MEMORY_SCOPE_AGENT);
      }
      __syncthreads();
    }
  }
  __syncthreads();
  if (tid == 0) {
    asm volatile("s_waitcnt vmcnt(0)" ::: "memory");   // ksplit stores at L3
    __hip_atomic_store(&sflag[b * 31 + s], 1,
                       __ATOMIC_RELAXED, __HIP_MEMORY_SCOPE_AGENT);
  }
}

// ---- walk body: polls its sentence's 31 score flags, then DFS ----
__device__ void walk_body(const int* __restrict__ ksplit, const int* __restrict__ len,
                          int* __restrict__ meta, int* __restrict__ sflag, int b)
{
  const int tid = threadIdx.x;
  if (tid < 64) {
    int ok;
    do {
      int v = 1;
      if (tid < 31)
        v = __hip_atomic_load(&sflag[b * 31 + tid], __ATOMIC_RELAXED,
                              __HIP_MEMORY_SCOPE_AGENT);
      ok = (v != 0);
    } while (__all(ok) == 0);
  }
  __syncthreads();
  __shared__ int ks[32 * 33];
  __shared__ int stk[96];
  for (int i = tid; i < 32 * 33; i += 256)
    ks[i] = __hip_atomic_load(&ksplit[b * 1056 + i], __ATOMIC_RELAXED,
                              __HIP_MEMORY_SCOPE_AGENT);
  __syncthreads();
  if (tid != 0) return;
  int* own = meta;
  int* lt = meta + 512;
  int* li = meta + 1024;
  int* rt = meta + 1536;
  int* ri = meta + 2048;
  int* dep = meta + 2560;
  int* nn = meta + 3072;
  int* dcnt = meta + 3088;
  int* lcnt = meta + 3120;
  int* dlist = meta + 3152;
  int* llist = meta + 19536;
  int sp = 0, nn_ = 1;
  stk[0] = 0; stk[1] = len[b]; stk[2] = 0;
  sp = 1;
  while (sp > 0) {
    sp--;
    const int s = stk[sp * 3], eN = stk[sp * 3 + 1], nid = stk[sp * 3 + 2];
    const int l = eN - s;
    const int k = ks[s * 33 + l];
    const int m = b * 32 + nid;
    own[m] = s + k;
    if (k == 0) { lt[m] = 0; li[m] = 0; }
    else if (k == 1) { lt[m] = 1; li[m] = s; }
    else {
      const int id = nn_++;
      lt[m] = 2; li[m] = id;
      stk[sp * 3] = s; stk[sp * 3 + 1] = s + k; stk[sp * 3 + 2] = id; sp++;
    }
    const int rl = l - k - 1;
    if (rl == 0) { rt[m] = 0; ri[m] = 0; }
    else if (rl == 1) { rt[m] = 1; ri[m] = s + k + 1; }
    else {
      const int id = nn_++;
      rt[m] = 2; ri[m] = id;
      stk[sp * 3] = s + k + 1; stk[sp * 3 + 1] = eN; stk[sp * 3 + 2] = id; sp++;
    }
  }
  nn[b] = nn_;
  for (int i = nn_ - 1; i >= 0; --i) {
    const int m = b * 32 + i;
    int d = 1;
    if (lt[m] == 2) d = max(d, dep[b * 32 + li[m]] + 1);
    if (rt[m] == 2) d = max(d, dep[b * 32 + ri[m]] + 1);
    dep[m] = d;
  }
  for (int i = 0; i < nn_; ++i) {
    const int m = b * 32 + i;
    const int r = dep[m];
    const int idx = atomicAdd(&dcnt[r], 1);
    dlist[r * 512 + idx] = m;
    if (lt[m] == 2 || rt[m] == 2) {
      const int lx = atomicAdd(&lcnt[r], 1);
      llist[r * 512 + lx] = m;
    }
  }
}

// ---- merged scan+score+Wc-conv+walk dispatch ----
// blocks 0-63 scan, 64-559 score, 560-687 Wc f32->bf16 conversion (hidden
// under scan's idle CUs), 688-703 walk (polls score flags). All 704 blocks
// co-resident (40KB LDS -> 4/CU = 1024 slots) -> polls deadlock-free.
__global__ __launch_bounds__(256)
void k_scansc(const float* Xf, const float* Xb,
              const unsigned short* WhfB, const unsigned short* WhbB,
              const float* bf, const float* bb, const int* len,
              unsigned short* hbB, float* cbuf, float* hs, float* cs, int* bar,
              const float* E1, const float* Wr1, const float* Wr2, int* ksplit,
              const float* Wc, unsigned short* WcB, int* sflag, int* meta)
{
  const int bid = blockIdx.x;
  if (bid < 64) {
    scan_body(Xf, Xb, WhfB, WhbB, bf, bb, len, hbB, cbuf, hs, cs, bar, bid);
  } else if (bid < 560) {
    const int idx = bid - 64;
    score_body(E1, Wr1, Wr2, len, ksplit, sflag, idx / 31, idx % 31);
  } else if (bid < 688) {
    const int idx = bid - 560;
    const int nf4 = 15728640 >> 2;
    for (int i = idx * 256 + threadIdx.x; i < nf4; i += 128 * 256) {
      const float4 v = *(const float4*)&Wc[i * 4];
      ushort4 o;
      o.x = f2bf(v.x); o.y = f2bf(v.y); o.z = f2bf(v.z); o.w = f2bf(v.w);
      *(ushort4*)&WcB[i * 4] = o;
    }
  } else {
    walk_body(ksplit, len, meta, sflag, bid - 688);
  }
}

// ---------------- build U (bf16) = [hl_leaf|0 , hr_leaf|0 , hx] per node ----------------
__global__ __launch_bounds__(256)
void k_ubuild(const float* __restrict__ hs, const int* __restrict__ meta,
              unsigned short* __restrict__ U)
{
  const int id = blockIdx.x, b = blockIdx.y;
  const int tid = threadIdx.x;
  const int* own = meta;
  const int* lt = meta + 512;
  const int* li = meta + 1024;
  const int* rt = meta + 1536;
  const int* ri = meta + 2048;
  const int* nn = meta + 3072;
  const int m = b * 32 + id;
  unsigned short* u = U + (size_t)m * K3;
  if (id >= nn[b]) {
    for (int i = tid; i < K3; i += 256) u[i] = 0;
    return;
  }
  const float* hl = (lt[m] == 1) ? hs + (size_t)(b * 32 + li[m]) * 1024 : nullptr;
  const float* hr = (rt[m] == 1) ? hs + (size_t)(b * 32 + ri[m]) * 1024 : nullptr;
  const float* hx = hs + (size_t)(b * 32 + own[m]) * 1024;
  for (int i = tid; i < 1024; i += 256) {
    u[i] = hl ? f2bf(hl[i]) : 0;
    u[1024 + i] = hr ? f2bf(hr[i]) : 0;
    u[2048 + i] = f2bf(hx[i]);
  }
}

// ---------------- fused tree rounds: hidden-index-partitioned ---------------
__global__ __launch_bounds__(256, 2)
void k_rounds(const unsigned short* __restrict__ WcB, const int* __restrict__ meta,
              unsigned short* __restrict__ nodehb,
              const float* __restrict__ gB, const float* __restrict__ cs,
              float* __restrict__ nodec,
              float* __restrict__ out, int* __restrict__ bar,
              const unsigned short* __restrict__ zpad)
{
  const int* lt = meta + 512;
  const int* li = meta + 1024;
  const int* rt = meta + 1536;
  const int* ri = meta + 2048;
  const int* dcnt = meta + 3088;
  const int* dlist = meta + 3152;
  __shared__ float scratch[4][16][17];
  __shared__ float gates[16][17];
  const int tid = threadIdx.x;
  const int bid = blockIdx.x;
  const int wave = tid >> 6, lane = tid & 63;
  const int l15 = lane & 15, quad = lane >> 4;
  const int j0 = bid * 2;
  const int cc = (l15 < 10) ? l15 : l15 - 10;
  const size_t wrow = (size_t)((cc >> 1) * 1024 + j0 + (cc & 1)) * K3;
  const int kbase = wave * 256 + quad * 8;
  short8 wreg[16];
#pragma unroll
  for (int i = 0; i < 8; ++i) {
    wreg[i]     = *(const short8*)&WcB[wrow + kbase + i * 32];
    wreg[8 + i] = *(const short8*)&WcB[wrow + 1024 + kbase + i * 32];
  }
  const int rnd = tid >> 4, rc = tid & 15;
  int bgen = 0;
  for (int r = 1; r <= 31; ++r) {
    const int cnt = dcnt[r];
    if (cnt == 0) break;
    if (r >= 2) { ++bgen; bar_rounds(bar, &bar[512], bid, bgen); }
    for (int c0 = 0; c0 < cnt; c0 += 16) {
      float gBv = 0.0f;
      if (rc < 10 && c0 + rnd < cnt) {
        const int nodeP = dlist[r * 512 + c0 + rnd];
        gBv = gB[(size_t)nodeP * H5 + (rc >> 1) * 1024 + j0 + (rc & 1)];
      }
      const int ma = c0 + l15;
      const unsigned short* pl = zpad;
      const unsigned short* pr = zpad;
      if (ma < cnt) {
        const int node = dlist[r * 512 + ma];
        const int base = node & ~31;
        if (lt[node] == 2) pl = nodehb + (size_t)(base + li[node]) * 1024;
        if (rt[node] == 2) pr = nodehb + (size_t)(base + ri[node]) * 1024;
      }
      short8 al[8], ar[8];
#pragma unroll
      for (int i = 0; i < 8; ++i)
        asm volatile("global_load_dwordx4 %0, %1, off sc0 sc1"
                     : "=&v"(al[i]) : "v"(pl + kbase + i * 32));
#pragma unroll
      for (int i = 0; i < 8; ++i)
        asm volatile("global_load_dwordx4 %0, %1, off sc0 sc1"
                     : "=&v"(ar[i]) : "v"(pr + kbase + i * 32));
      floatx4 acc = (floatx4){0.f, 0.f, 0.f, 0.f};
      asm volatile("s_waitcnt vmcnt(8)" ::: "memory");
      __builtin_amdgcn_sched_barrier(0);
#pragma unroll
      for (int ks = 0; ks < 8; ++ks)
        acc = __builtin_amdgcn_mfma_f32_16x16x32_bf16(al[ks], wreg[ks], acc, 0, 0, 0);
      asm volatile("s_waitcnt vmcnt(0)" ::: "memory");
      __builtin_amdgcn_sched_barrier(0);
#pragma unroll
      for (int ks = 0; ks < 8; ++ks)
        acc = __builtin_amdgcn_mfma_f32_16x16x32_bf16(ar[ks], wreg[8 + ks], acc, 0, 0, 0);
      __syncthreads();
#pragma unroll
      for (int i = 0; i < 4; ++i)
        scratch[wave][quad * 4 + i][l15] = acc[i];
      __syncthreads();
      if (rc < 10)
        gates[rnd][rc] = gBv + scratch[0][rnd][rc] + scratch[1][rnd][rc]
                             + scratch[2][rnd][rc] + scratch[3][rnd][rc];
      __syncthreads();
      if (tid < 16) {
        const int mc = c0 + tid;
        if (mc < cnt) {
          const int node = dlist[r * 512 + mc];
          const int base = node & ~31;
          const int ltv = lt[node], rtv = rt[node];
          const float* clp = (ltv == 2) ? &nodec[(size_t)(base + li[node]) * 1024]
                           : (ltv == 1) ? &cs[(size_t)(base + li[node]) * 1024] : nullptr;
          const float* crp = (rtv == 2) ? &nodec[(size_t)(base + ri[node]) * 1024]
                           : (rtv == 1) ? &cs[(size_t)(base + ri[node]) * 1024] : nullptr;
          unsigned int pk = 0;
#pragma unroll
          for (int jj = 0; jj < 2; ++jj) {
            const int j = j0 + jj;
            const float gi  = gates[tid][0 + jj];
            const float gfl = gates[tid][2 + jj];
            const float gfr = gates[tid][4 + jj];
            const float gu  = gates[tid][6 + jj];
            const float go  = gates[tid][8 + jj];
            const float cl = clp ? clp[j] : 0.0f;
            const float cr = crp ? crp[j] : 0.0f;
            const float c_ = sigf(gfl) * cl + sigf(gfr) * cr + sigf(gi) * tanhf(gu);
            const float h  = sigf(go) * tanhf(c_);
            nodec[(size_t)node * 1024 + j] = c_;
            pk |= ((unsigned int)f2bf(h)) << (16 * jj);
            if ((node & 31) == 0) {
              const int b = node >> 5;
              out[b * 1024 + j] = h;
              out[16384 + b * 1024 + j] = c_;
            }
          }
          asm volatile("global_store_dword %0, %1, off sc0 sc1"
                       :: "v"(nodehb + (size_t)node * 1024 + j0), "v"(pk)
                       : "memory");
        }
      }
    }
  }
}

extern "C" void kernel_launch(void* const* d_in, const int* in_sizes, int n_in,
                              void* d_out, int out_size, void* d_ws, size_t ws_size,
                              hipStream_t stream) {
  const float* emb = (const float*)d_in[0];
  const int* len = (const int*)d_in[1];
  const float* Wihf = (const float*)d_in[2];
  const float* Whhf = (const float*)d_in[3];
  const float* bf = (const float*)d_in[4];
  const float* Wihb = (const float*)d_in[5];
  const float* Whhb = (const float*)d_in[6];
  const float* bb = (const float*)d_in[7];
  const float* Wr1 = (const float*)d_in[8];
  const float* Wr2 = (const float*)d_in[9];
  const float* Wc = (const float*)d_in[10];
  const float* bc = (const float*)d_in[11];
  float* out = (float*)d_out;

  float* ws = (float*)d_ws;
  float* Xf = ws;                                         // 1048576 f
  float* Xb = Xf + 1048576;                               // 1048576 f
  float* hs = Xb + 1048576;                               // 524288 f
  float* cs = hs + 524288;                                // 524288 f
  float* E1 = cs + 524288;                                // 131072 f
  unsigned short* U = (unsigned short*)(E1 + 131072);     // 786432 f
  float* gB = (float*)U + 786432;                         // 2621440 f
  float* nodeh = gB + 2621440;                            // 524288 f (unused)
  float* nodec = nodeh + 524288;                          // 524288 f
  unsigned short* nodehb = (unsigned short*)(nodec + 524288);     // 262144 f
  float* cbuf = (float*)nodehb + 262144;                  // 32768 f
  unsigned short* hbB = (unsigned short*)(cbuf + 32768);  // 16384 f
  unsigned short* WcB = (unsigned short*)((float*)hbB + 16384);   // 7864320 f
  unsigned short* WihfB = WcB + 15728640;                 // 1048576 sh
  unsigned short* WihbB = WihfB + 1048576;
  unsigned short* WhhfB = WihbB + 1048576;
  unsigned short* WhhbB = WhhfB + 1048576;
  unsigned short* embB = WhhbB + 1048576;                 // 262144 sh
  int* meta = (int*)(embB + 262144);                      // ~36K ints
  int* ksplit = meta + 36096;                             // 16*1056 ints
  int* bar = ksplit + 16896;                              // 1024 ints barrier state
  unsigned short* zpad = (unsigned short*)(bar + 1024);   // 1024 sh (512 int-eq)
  int* sflag = bar + 1536;                                // 512 ints score flags
  // bar layout: [0..511] rounds flags, [512] rounds gen,
  //             [528..559] scan flags dir0, [560..591] scan flags dir1

  // merged zero: cbuf + depth counters + barrier/zpad/sflag state
  k_zero3<<<128, 256, 0, stream>>>(cbuf, 49152, (float*)(meta + 3088), 64,
                                   (float*)bar, 2048);
  // bf16 conversions for scan/proj inputs (Wc conversion hidden in k_scansc)
  k_conv5<<<dim3(512, 5), 256, 0, stream>>>(
      emb, embB, 262144, Wihf, WihfB, 1048576, Wihb, WihbB, 1048576,
      Whhf, WhhfB, 1048576, Whhb, WhhbB, 1048576);
  // merged E1 rank projection + input projections
  k_proj<<<160, 256, 0, stream>>>(emb, Wr1, E1, embB, WihfB, WihbB, Xf, Xb);
  // merged recurrent scan + split scoring + Wc conversion + DFS walk
  k_scansc<<<704, 256, 0, stream>>>(Xf, Xb, WhhfB, WhhbB, bf, bb, len, hbB,
                                    cbuf, hs, cs, bar, E1, Wr1, Wr2, ksplit,
                                    Wc, WcB, sflag, meta);
  // precomputable part of every compose
  k_ubuild<<<dim3(32, 16), 256, 0, stream>>>(hs, meta, U);
  k_mfma_gemm<<<320, 256, 0, stream>>>(U, WcB, bc, gB);
  // fused tree rounds (512 blocks, 1 monitor barrier/round)
  k_rounds<<<512, 256, 0, stream>>>(WcB, meta, nodehb, gB, cs,
                                    nodec, out, bar, zpad);
}